// Round 11
// baseline (5051.407 us; speedup 1.0000x reference)
//
#include <hip/hip_runtime.h>
#include <hip/hip_cooperative_groups.h>
#include <math.h>

namespace cg = cooperative_groups;

#define NITEMS 50000
#define NROWS 50001
#define NP 50048          // padded row count (391*128)
#define DD 512
#define HH 512
#define TT 16
#define NEGV (-1e18f)
#define NGRP 782          // 391 groups x 2 partials
#define NGROUPS 391
#define HOPBLK 2048       // discrete-fallback hop grid
#define NBC 256           // coop blocks (known-good launch config)
#define NTC 512           // coop threads/block

typedef unsigned long long ull;
typedef unsigned short ushort;
typedef short short8 __attribute__((ext_vector_type(8)));
typedef float f32x4 __attribute__((ext_vector_type(4)));

__device__ __forceinline__ unsigned fkey(float f) {
  unsigned u = __float_as_uint(f);
  return (u & 0x80000000u) ? ~u : (u | 0x80000000u);
}
__device__ __forceinline__ float ftanh(float x) {
  float e = __builtin_amdgcn_exp2f(x * 2.885390081777927f);
  return 1.f - 2.f * __builtin_amdgcn_rcpf(e + 1.f);
}
__device__ __forceinline__ float fexp(float x) {
  return __builtin_amdgcn_exp2f(x * 1.4426950408889634f);
}
__device__ __forceinline__ ushort rne1(float a) {
  unsigned u = __float_as_uint(a);
  return (ushort)((u + 0x7fffu + ((u >> 16) & 1u)) >> 16);
}
__device__ __forceinline__ float bf2f(ushort h) { return __uint_as_float((unsigned)h << 16); }
__device__ __forceinline__ unsigned pack_bf16(float a, float b) {
  return (unsigned)rne1(a) | ((unsigned)rne1(b) << 16);
}
__device__ __forceinline__ float bflo(unsigned u) { return __uint_as_float(u << 16); }
__device__ __forceinline__ float bfhi(unsigned u) { return __uint_as_float(u & 0xffff0000u); }

__device__ __forceinline__ void gl_lds16(const void* g, void* l) {
#if __has_builtin(__builtin_amdgcn_global_load_lds)
  __builtin_amdgcn_global_load_lds((const __attribute__((address_space(1))) unsigned*)g,
                                   (__attribute__((address_space(3))) unsigned*)l, 16, 0, 0);
#else
  const int lane = threadIdx.x & 63;
  *(uint4*)((char*)l + lane * 16) = *(const uint4*)g;
#endif
}

#define MFMA(a, b, c) __builtin_amdgcn_mfma_f32_16x16x32_bf16(a, b, c, 0, 0, 0)

// ---------------- A -> (Ahi, Alo) bf16 [NP][512] ----------------
__global__ void k_convA(const float* __restrict__ A0, const float* __restrict__ stoprow,
                        ushort* __restrict__ Ahi, ushort* __restrict__ Alo) {
  const size_t t = (size_t)blockIdx.x * 256 + threadIdx.x;
  const size_t base = t * 8;
  const int row = (int)(base >> 9);
  float v[8];
  if (row < NITEMS) {
    const float4* p = (const float4*)(A0 + base);
    float4 x = p[0], y = p[1];
    v[0] = x.x; v[1] = x.y; v[2] = x.z; v[3] = x.w;
    v[4] = y.x; v[5] = y.y; v[6] = y.z; v[7] = y.w;
  } else if (row == NITEMS) {
    const float4* p = (const float4*)(stoprow + (base & 511));
    float4 x = p[0], y = p[1];
    v[0] = x.x; v[1] = x.y; v[2] = x.z; v[3] = x.w;
    v[4] = y.x; v[5] = y.y; v[6] = y.z; v[7] = y.w;
  } else {
#pragma unroll
    for (int j = 0; j < 8; ++j) v[j] = 0.f;
  }
  unsigned hw[4], lw[4];
#pragma unroll
  for (int j = 0; j < 4; ++j) {
    float a0 = v[2 * j], a1 = v[2 * j + 1];
    ushort h0 = rne1(a0), h1 = rne1(a1);
    hw[j] = (unsigned)h0 | ((unsigned)h1 << 16);
    lw[j] = pack_bf16(a0 - bf2f(h0), a1 - bf2f(h1));
  }
  *(uint4*)(Ahi + base) = make_uint4(hw[0], hw[1], hw[2], hw[3]);
  *(uint4*)(Alo + base) = make_uint4(lw[0], lw[1], lw[2], lw[3]);
}

// ---------------- W [k][n] -> transposed bf16 ----------------
__global__ void k_convBT(const float* __restrict__ W, ushort* __restrict__ WhiT,
                         ushort* __restrict__ WloT) {
  const int n = blockIdx.x;
  const int k0 = threadIdx.x * 2;
  float a0 = W[(size_t)k0 * 512 + n];
  float a1 = W[(size_t)(k0 + 1) * 512 + n];
  ushort h0 = rne1(a0), h1 = rne1(a1);
  *(unsigned*)(WhiT + (size_t)n * 512 + k0) = (unsigned)h0 | ((unsigned)h1 << 16);
  *(unsigned*)(WloT + (size_t)n * 512 + k0) = pack_bf16(a0 - bf2f(h0), a1 - bf2f(h1));
}

// ---------------- MFMA GEMM (verified R10) ----------------
template <int TR>
__launch_bounds__(256, 2)
__global__ void k_mfma(const ushort* __restrict__ Ahi, const ushort* __restrict__ Alo,
                       const ushort* __restrict__ BhT, const ushort* __restrict__ BlT,
                       ushort* __restrict__ C) {
  __shared__ __align__(16) char lds[65536];
  char* sA0 = lds;
  char* sA1 = lds + 16384;
  char* sB0 = lds + 32768;
  char* sB1 = lds + 49152;
  const int tid = threadIdx.x;
  const int lane = tid & 63, w = tid >> 6;
  const int lid = blockIdx.y * 4 + blockIdx.x;
  const int xcd = lid & 7, pos = lid >> 3;
  const int orig = ((xcd < 4) ? xcd * 196 : 784 + (xcd - 4) * 195) + pos;
  const int m0 = (orig >> 2) * 128, n0 = (orig & 3) * 128;
  const int aR0 = (w & 1) * 64, bR0 = (w >> 1) * 64;

  f32x4 acc[4][4];
  const f32x4 z4 = {0.f, 0.f, 0.f, 0.f};
#pragma unroll
  for (int i = 0; i < 4; ++i)
#pragma unroll
    for (int j = 0; j < 4; ++j) acc[i][j] = z4;

#define STAGE_ALL(KT)                                                                     \
  {                                                                                       \
    _Pragma("unroll") for (int i = 0; i < 4; ++i) {                                       \
      const int row = i * 32 + (tid >> 3);                                                \
      const int kb = ((tid & 7) << 4) ^ ((row & 7) << 4);                                 \
      const int ldso = i * 4096 + (w << 10);                                              \
      gl_lds16((const char*)(Ahi + ((size_t)(m0 + row) << 9) + (KT)) + kb, sA0 + ldso);   \
      gl_lds16((const char*)(Alo + ((size_t)(m0 + row) << 9) + (KT)) + kb, sA1 + ldso);   \
      gl_lds16((const char*)(BhT + ((size_t)(n0 + row) << 9) + (KT)) + kb, sB0 + ldso);   \
      gl_lds16((const char*)(BlT + ((size_t)(n0 + row) << 9) + (KT)) + kb, sB1 + ldso);   \
    }                                                                                     \
  }

  STAGE_ALL(0)
  __syncthreads();
  for (int c = 0; c < 8; ++c) {
#pragma unroll
    for (int ks = 0; ks < 2; ++ks) {
      short8 ah[4], al[4], bh[4], bl[4];
      const int kbb = ks * 64 + ((lane >> 4) << 4);
#pragma unroll
      for (int f = 0; f < 4; ++f) {
        const int ra = aR0 + f * 16 + (lane & 15);
        const int oa = ra * 128 + (kbb ^ ((ra & 7) << 4));
        ah[f] = *(const short8*)(sA0 + oa);
        al[f] = *(const short8*)(sA1 + oa);
        const int rb = bR0 + f * 16 + (lane & 15);
        const int ob = rb * 128 + (kbb ^ ((rb & 7) << 4));
        bh[f] = *(const short8*)(sB0 + ob);
        bl[f] = *(const short8*)(sB1 + ob);
      }
#pragma unroll
      for (int mf = 0; mf < 4; ++mf)
#pragma unroll
        for (int nf = 0; nf < 4; ++nf) {
          acc[mf][nf] = MFMA(ah[mf], bh[nf], acc[mf][nf]);
          acc[mf][nf] = MFMA(ah[mf], bl[nf], acc[mf][nf]);
          acc[mf][nf] = MFMA(al[mf], bh[nf], acc[mf][nf]);
        }
    }
    if (c < 7) {
      __syncthreads();
      STAGE_ALL((c + 1) * 64)
      __syncthreads();
    }
  }
#undef STAGE_ALL

#pragma unroll
  for (int mf = 0; mf < 4; ++mf)
#pragma unroll
    for (int nf = 0; nf < 4; ++nf) {
      const f32x4 a = acc[mf][nf];
      const int n = n0 + bR0 + nf * 16 + (lane & 15);
      const int mb = m0 + aR0 + mf * 16 + ((lane >> 4) << 2);
      if (TR) {
        ushort* p = C + (size_t)n * NP + mb;
        *(uint2*)p = make_uint2(pack_bf16(a.x, a.y), pack_bf16(a.z, a.w));
      } else {
        C[(size_t)(mb + 0) * 512 + n] = rne1(a.x);
        C[(size_t)(mb + 1) * 512 + n] = rne1(a.y);
        C[(size_t)(mb + 2) * 512 + n] = rne1(a.z);
        C[(size_t)(mb + 3) * 512 + n] = rne1(a.w);
      }
    }
}

// ======================================================================
//                     COOPERATIVE LOOP KERNEL
// ======================================================================
struct P {
  const float *attn_mem, *stoprow, *init_h, *init_c, *init_i;
  const float *attn_wq, *attn_v, *hop_wq, *hop_v;
  const float *w_ih, *w_hh, *b_ih, *b_hh, *gumbel;
  const ushort *attn_featT, *hop_feat;
  float* sc;
  int* sel;
  float *qp, *bZh, *bZa;
  ull* bkey;
  float *gates, *hv, *cv0, *cv1, *b1, *b2;
  int *done2, *xrow2;
  float* outf;
};

union SM {
  struct { float rz[NTC]; ull rk[NTC]; } r;
  struct { float h[512]; float red[512]; } bc;
  struct { float sz[8]; float qbuf[8][512]; } d;
  struct { float red[512]; float qn[512]; } ef;
  struct { float spart[8][128]; } g;
};

__launch_bounds__(NTC, 2)
__global__ void k_loop(P p) {
  cg::grid_group grid = cg::this_grid();
  __shared__ SM sm;
  const int tid = threadIdx.x, blk = blockIdx.x;
  const int w = tid >> 6, lane = tid & 63;

  for (int i = blk * NTC + tid; i < NROWS; i += NBC * NTC) p.sel[i] = 0;
  grid.sync();

  for (int t = 0; t <= TT; ++t) {
    // ===== phase A: finalize step t-1 (redundant in all blocks) + LSTM gates =====
    int xrow = -1;
    if (t > 0) {
      float Zl = 0.f;
      ull Kl = 0;
      for (int i = tid; i < NGRP; i += NTC) {
        Zl += p.bZa[i];
        ull k = p.bkey[i];
        if (k > Kl) Kl = k;
      }
      sm.r.rz[tid] = Zl;
      sm.r.rk[tid] = Kl;
      __syncthreads();
      for (int s = 256; s > 0; s >>= 1) {
        if (tid < s) {
          sm.r.rz[tid] += sm.r.rz[tid + s];
          if (sm.r.rk[tid + s] > sm.r.rk[tid]) sm.r.rk[tid] = sm.r.rk[tid + s];
        }
        __syncthreads();
      }
      const float Z = sm.r.rz[0];
      const ull K = sm.r.rk[0];
      __syncthreads();
      const int out = NITEMS - (int)(unsigned)(K & 0xffffffffull);
      const int d_in = (t == 1) ? 0 : p.done2[(t - 1) & 1];
      const int xprev = (t == 1) ? -1 : p.xrow2[(t - 1) & 1];
      const int nd = d_in | (out == NITEMS);
      xrow = nd ? xprev : out;
      if (blk == 0 && tid == 0) {
        p.outf[t - 1] = (float)(d_in ? NITEMS : out);
        p.outf[TT + t - 1] = d_in ? 0.f : (p.sc[out] - logf(Z));
        if (!d_in) p.sel[out] = 1;
        p.done2[t & 1] = nd;
        p.xrow2[t & 1] = xrow;
      }
    }
    if (t == TT) break;
    {
      // gates row r = blk*8 + w (2048 rows)
      const int r = blk * 8 + w;
      const float* xp = (xrow < 0) ? p.init_i
                                   : ((xrow == NITEMS) ? p.stoprow : p.attn_mem + (size_t)xrow * DD);
      const float* hp = (t == 0) ? p.init_h : p.hv;
      const float4* x4 = (const float4*)xp;
      const float4* h4 = (const float4*)hp;
      const float4* wi = (const float4*)(p.w_ih + (size_t)r * DD);
      const float4* wh = (const float4*)(p.w_hh + (size_t)r * DD);
      float s = 0.f;
      float4 a, ww;
      a = x4[lane * 2];     ww = wi[lane * 2];     s += a.x * ww.x + a.y * ww.y + a.z * ww.z + a.w * ww.w;
      a = x4[lane * 2 + 1]; ww = wi[lane * 2 + 1]; s += a.x * ww.x + a.y * ww.y + a.z * ww.z + a.w * ww.w;
      a = h4[lane * 2];     ww = wh[lane * 2];     s += a.x * ww.x + a.y * ww.y + a.z * ww.z + a.w * ww.w;
      a = h4[lane * 2 + 1]; ww = wh[lane * 2 + 1]; s += a.x * ww.x + a.y * ww.y + a.z * ww.z + a.w * ww.w;
#pragma unroll
      for (int off = 32; off > 0; off >>= 1) s += __shfl_xor(s, off);
      if (lane == 0) p.gates[r] = s + p.b_ih[r] + p.b_hh[r];
    }
    grid.sync();

    // ===== phase B: h,c update (redundant x8) + b1 = h @ hop_wq =====
    if (blk < 8) {
      const float* csrc = (t == 0) ? p.init_c : ((t & 1) ? p.cv1 : p.cv0);
      float* cdst = (t & 1) ? p.cv0 : p.cv1;
      const float gi = p.gates[tid], gf = p.gates[512 + tid], gg = p.gates[1024 + tid],
                  go = p.gates[1536 + tid];
      const float si = 1.f / (1.f + expf(-gi));
      const float sf = 1.f / (1.f + expf(-gf));
      const float so = 1.f / (1.f + expf(-go));
      const float cn = sf * csrc[tid] + si * tanhf(gg);
      const float hval = so * tanhf(cn);
      sm.bc.h[tid] = hval;
      if (blk == 0) { cdst[tid] = cn; p.hv[tid] = hval; }
      __syncthreads();
      const int cc = tid & 63, q = tid >> 6;
      const int j = blk * 64 + cc;
      float pb = 0.f;
      for (int i = q * 64; i < q * 64 + 64; ++i)
        pb = fmaf(sm.bc.h[i], p.hop_wq[(size_t)i * HH + j], pb);
      sm.bc.red[tid] = pb;
      __syncthreads();
      if (tid < 64) {
        float a2 = 0.f;
#pragma unroll
        for (int g2 = 0; g2 < 8; ++g2) a2 += sm.bc.red[tid + 64 * g2];
        p.b1[blk * 64 + tid] = a2;
      }
    }
    grid.sync();

    // ===== phase D: hop sweep (2048 waves, prefetch-pipelined) =====
    {
      float bv[8], vv[8], qa[8];
#pragma unroll
      for (int j = 0; j < 8; ++j) {
        bv[j] = p.b1[lane * 8 + j];
        vv[j] = p.hop_v[lane * 8 + j];
        qa[j] = 0.f;
      }
      float Z = 0.f;
      const int wv = blk * 8 + w;
      int m = wv;
      uint4 U = ((const uint4*)(p.hop_feat + ((size_t)m * HH)))[lane];
      while (m < NROWS) {
        const int mn = m + 2048;
        const uint4 Un = ((const uint4*)(p.hop_feat + ((size_t)(mn < NROWS ? mn : 0) * HH)))[lane];
        float f[8] = {bflo(U.x), bfhi(U.x), bflo(U.y), bfhi(U.y),
                      bflo(U.z), bfhi(U.z), bflo(U.w), bfhi(U.w)};
        float s = 0.f;
#pragma unroll
        for (int j = 0; j < 8; ++j) s += ftanh(f[j] + bv[j]) * vv[j];
#pragma unroll
        for (int off = 32; off > 0; off >>= 1) s += __shfl_xor(s, off);
        const float e = fexp(s);
        Z += e;
#pragma unroll
        for (int j = 0; j < 8; ++j) qa[j] = fmaf(e, f[j], qa[j]);
        U = Un;
        m = mn;
      }
      if (lane == 0) sm.d.sz[w] = Z;
#pragma unroll
      for (int j = 0; j < 8; ++j) sm.d.qbuf[w][lane * 8 + j] = qa[j];
      __syncthreads();
      float a0 = 0.f;
#pragma unroll
      for (int w2 = 0; w2 < 8; ++w2) a0 += sm.d.qbuf[w2][tid];
      p.qp[(size_t)blk * 512 + tid] = a0;
      if (tid == 0)
        p.bZh[blk] = sm.d.sz[0] + sm.d.sz[1] + sm.d.sz[2] + sm.d.sz[3] +
                     sm.d.sz[4] + sm.d.sz[5] + sm.d.sz[6] + sm.d.sz[7];
    }
    grid.sync();

    // ===== phase EF: qn combine + b2 = qn @ attn_wq (8 blocks) =====
    if (blk < 8) {
      sm.ef.red[tid] = (tid < NBC) ? p.bZh[tid] : 0.f;
      __syncthreads();
      for (int s = 256; s > 0; s >>= 1) {
        if (tid < s) sm.ef.red[tid] += sm.ef.red[tid + s];
        __syncthreads();
      }
      const float Z = sm.ef.red[0];
      __syncthreads();
      float acc = 0.f;
      for (int pp = 0; pp < NBC; ++pp) acc += p.qp[(size_t)pp * 512 + tid];
      sm.ef.qn[tid] = acc / Z;
      __syncthreads();
      const int jj = tid & 63, seg = tid >> 6;
      const int j = blk * 64 + jj;
      float pb = 0.f;
      for (int i = seg * 64; i < seg * 64 + 64; ++i)
        pb = fmaf(sm.ef.qn[i], p.attn_wq[(size_t)i * HH + j], pb);
      sm.ef.red[tid] = pb;
      __syncthreads();
      if (tid < 64) {
        float a2 = 0.f;
#pragma unroll
        for (int g2 = 0; g2 < 8; ++g2) a2 += sm.ef.red[tid + 64 * g2];
        p.b2[blk * 64 + tid] = a2;
      }
    }
    grid.sync();

    // ===== phase G: attn transposed sweep (groups of 128 rows, grid-stride) =====
    {
      const float* gum = p.gumbel + (size_t)t * NROWS;
      for (int g = blk; g < NGROUPS; g += NBC) {
        const int mb = g * 128 + lane * 2;
        const int h0 = w * 64;
        const ushort* fp = p.attn_featT + (size_t)h0 * NP + mb;
        float acc0 = 0.f, acc1 = 0.f;
#pragma unroll 8
        for (int hh = 0; hh < 64; ++hh) {
          const unsigned u = *(const unsigned*)fp;
          fp += NP;
          const float bb = p.b2[h0 + hh], vv = p.attn_v[h0 + hh];
          acc0 += ftanh(bflo(u) + bb) * vv;
          acc1 += ftanh(bfhi(u) + bb) * vv;
        }
        sm.g.spart[w][lane * 2] = acc0;
        sm.g.spart[w][lane * 2 + 1] = acc1;
        __syncthreads();
        if (w < 2) {
          const int idx = w * 64 + lane;
          const int m = g * 128 + idx;
          float s = 0.f;
#pragma unroll
          for (int w2 = 0; w2 < 8; ++w2) s += sm.g.spart[w2][idx];
          const bool valid = (m < NROWS);
          float Z;
          ull key;
          if (valid) {
            float se = p.sel[m] ? NEGV : s;
            p.sc[m] = se;
            key = ((ull)fkey(se + gum[m]) << 32) | (unsigned)(NITEMS - m);
            Z = fexp(se);
          } else {
            key = 0;
            Z = 0.f;
          }
#pragma unroll
          for (int off = 32; off > 0; off >>= 1) {
            Z += __shfl_xor(Z, off);
            ull Ko = __shfl_xor(key, off);
            if (Ko > key) key = Ko;
          }
          if (lane == 0) { p.bZa[g * 2 + w] = Z; p.bkey[g * 2 + w] = key; }
        }
        __syncthreads();
      }
    }
    grid.sync();
  }
}

// ======================================================================
//                     DISCRETE FALLBACK (verified R9/R10)
// ======================================================================
__global__ void k_zero(int* __restrict__ sel) {
  int i = blockIdx.x * 256 + threadIdx.x;
  if (i < NROWS) sel[i] = 0;
}

__launch_bounds__(256)
__global__ void k_final_gates(const float* __restrict__ bZa, const ull* __restrict__ bkey,
                              const float* __restrict__ sc,
                              int* __restrict__ sel, int* __restrict__ done2,
                              int* __restrict__ xrow2, float* __restrict__ outf,
                              const float* __restrict__ attn_mem, const float* __restrict__ stoprow,
                              const float* __restrict__ init_i, const float* __restrict__ init_h,
                              const float* __restrict__ hv,
                              const float* __restrict__ w_ih, const float* __restrict__ w_hh,
                              const float* __restrict__ b_ih, const float* __restrict__ b_hh,
                              float* __restrict__ gates, int t) {
  __shared__ float redz[256];
  __shared__ ull redk[256];
  const int tid = threadIdx.x, blk = blockIdx.x;
  const int w = tid >> 6, lane = tid & 63;
  int xrow = -1;
  if (t > 0) {
    float Zl = 0.f;
    ull Kl = 0;
    for (int i = tid; i < NGRP; i += 256) {
      Zl += bZa[i];
      ull k = bkey[i];
      if (k > Kl) Kl = k;
    }
    redz[tid] = Zl;
    redk[tid] = Kl;
    __syncthreads();
    for (int s2 = 128; s2 > 0; s2 >>= 1) {
      if (tid < s2) {
        redz[tid] += redz[tid + s2];
        if (redk[tid + s2] > redk[tid]) redk[tid] = redk[tid + s2];
      }
      __syncthreads();
    }
    const float Z = redz[0];
    const ull K = redk[0];
    const int out = NITEMS - (int)(unsigned)(K & 0xffffffffull);
    const int d_in = (t == 1) ? 0 : done2[(t - 1) & 1];
    const int xprev = (t == 1) ? -1 : xrow2[(t - 1) & 1];
    const int nd = d_in | (out == NITEMS);
    xrow = nd ? xprev : out;
    if (blk == 0 && tid == 0) {
      outf[t - 1] = (float)(d_in ? NITEMS : out);
      outf[TT + t - 1] = d_in ? 0.f : (sc[out] - logf(Z));
      if (!d_in) sel[out] = 1;
      done2[t & 1] = nd;
      xrow2[t & 1] = xrow;
    }
  }
  const int r = blk * 4 + w;
  const float* xp = (xrow < 0) ? init_i
                               : ((xrow == NITEMS) ? stoprow : attn_mem + (size_t)xrow * DD);
  const float* hp = (t == 0) ? init_h : hv;
  const float4* x4 = (const float4*)xp;
  const float4* h4 = (const float4*)hp;
  const float4* wi = (const float4*)(w_ih + (size_t)r * DD);
  const float4* wh = (const float4*)(w_hh + (size_t)r * DD);
  float s = 0.f;
  float4 a, ww;
  a = x4[lane * 2];     ww = wi[lane * 2];     s += a.x * ww.x + a.y * ww.y + a.z * ww.z + a.w * ww.w;
  a = x4[lane * 2 + 1]; ww = wi[lane * 2 + 1]; s += a.x * ww.x + a.y * ww.y + a.z * ww.z + a.w * ww.w;
  a = h4[lane * 2];     ww = wh[lane * 2];     s += a.x * ww.x + a.y * ww.y + a.z * ww.z + a.w * ww.w;
  a = h4[lane * 2 + 1]; ww = wh[lane * 2 + 1]; s += a.x * ww.x + a.y * ww.y + a.z * ww.z + a.w * ww.w;
#pragma unroll
  for (int off = 32; off > 0; off >>= 1) s += __shfl_xor(s, off);
  if (lane == 0) gates[r] = s + b_ih[r] + b_hh[r];
}

__launch_bounds__(256)
__global__ void k_hc_b1(const float* __restrict__ gates, const float* __restrict__ init_c,
                        float* __restrict__ cv0, float* __restrict__ cv1, float* __restrict__ hv,
                        const float* __restrict__ hop_wq, float* __restrict__ b1, int t) {
  __shared__ float h[512];
  __shared__ float red[256];
  const int tid = threadIdx.x, blk = blockIdx.x;
  const float* csrc = (t == 0) ? init_c : ((t & 1) ? cv1 : cv0);
  float* cdst = (t & 1) ? cv0 : cv1;
  for (int i = tid; i < 512; i += 256) {
    float gi = gates[i], gf = gates[512 + i], gg = gates[1024 + i], go = gates[1536 + i];
    float si = 1.f / (1.f + expf(-gi));
    float sf = 1.f / (1.f + expf(-gf));
    float so = 1.f / (1.f + expf(-go));
    float cn = sf * csrc[i] + si * tanhf(gg);
    float hval = so * tanhf(cn);
    h[i] = hval;
    if (blk == 0) { cdst[i] = cn; hv[i] = hval; }
  }
  __syncthreads();
  const int cc = tid & 63, q = tid >> 6;
  const int j = blk * 64 + cc;
  float pb = 0.f;
  for (int i = q * 128; i < q * 128 + 128; ++i) pb = fmaf(h[i], hop_wq[(size_t)i * HH + j], pb);
  red[tid] = pb;
  __syncthreads();
  if (tid < 64) b1[blk * 64 + tid] = red[tid] + red[tid + 64] + red[tid + 128] + red[tid + 192];
}

__launch_bounds__(256)
__global__ void k_hop(const ushort* __restrict__ feat, const float* __restrict__ bvec,
                      const float* __restrict__ v, float* __restrict__ qp,
                      float* __restrict__ bZh) {
  __shared__ float sz[4];
  __shared__ float qbuf[4][512];
  const int tid = threadIdx.x, blk = blockIdx.x;
  const int w = tid >> 6, lane = tid & 63;
  const int wv = blk * 4 + w;
  float bv[8], vv[8], qa[8];
#pragma unroll
  for (int j = 0; j < 8; ++j) { bv[j] = bvec[lane * 8 + j]; vv[j] = v[lane * 8 + j]; qa[j] = 0.f; }
  float Z = 0.f;
  for (int m = wv; m < NROWS; m += 4 * HOPBLK) {
    const uint4* fp = (const uint4*)(feat + (size_t)m * HH);
    uint4 U = fp[lane];
    float f[8] = {bflo(U.x), bfhi(U.x), bflo(U.y), bfhi(U.y),
                  bflo(U.z), bfhi(U.z), bflo(U.w), bfhi(U.w)};
    float s = 0.f;
#pragma unroll
    for (int j = 0; j < 8; ++j) s += ftanh(f[j] + bv[j]) * vv[j];
#pragma unroll
    for (int off = 32; off > 0; off >>= 1) s += __shfl_xor(s, off);
    const float e = fexp(s);
    Z += e;
#pragma unroll
    for (int j = 0; j < 8; ++j) qa[j] = fmaf(e, f[j], qa[j]);
  }
  if (lane == 0) sz[w] = Z;
#pragma unroll
  for (int j = 0; j < 8; ++j) qbuf[w][lane * 8 + j] = qa[j];
  __syncthreads();
  float a0 = 0.f, a1 = 0.f;
#pragma unroll
  for (int w2 = 0; w2 < 4; ++w2) { a0 += qbuf[w2][tid]; a1 += qbuf[w2][tid + 256]; }
  qp[(size_t)blk * 512 + tid] = a0;
  qp[(size_t)blk * 512 + tid + 256] = a1;
  if (tid == 0) bZh[blk] = sz[0] + sz[1] + sz[2] + sz[3];
}

__launch_bounds__(1024)
__global__ void k_qn(const float* __restrict__ qp, const float* __restrict__ bZh,
                     float* __restrict__ qn) {
  __shared__ float red[1024];
  const int tid = threadIdx.x;
  red[tid] = bZh[tid] + bZh[tid + 1024];
  __syncthreads();
  for (int s2 = 512; s2 > 0; s2 >>= 1) {
    if (tid < s2) red[tid] += red[tid + s2];
    __syncthreads();
  }
  const float Z = red[0];
  __syncthreads();
  const int cc = tid & 31, q = tid >> 5;
  const int col = blockIdx.x * 32 + cc;
  float acc = 0.f;
  for (int p = q * 64; p < q * 64 + 64; ++p) acc += qp[(size_t)p * 512 + col];
  red[tid] = acc;
  __syncthreads();
  if (tid < 32) {
    float a = 0.f;
#pragma unroll
    for (int g = 0; g < 32; ++g) a += red[tid + 32 * g];
    qn[blockIdx.x * 32 + tid] = a / Z;
  }
}

__launch_bounds__(256)
__global__ void k_gemv(const float* __restrict__ q, const float* __restrict__ W,
                       float* __restrict__ out) {
  __shared__ float lds[256];
  const int tid = threadIdx.x;
  const int cc = tid & 63, rs = tid >> 6;
  const int j = blockIdx.x * 64 + cc;
  float p = 0.f;
  for (int i = rs * 128; i < rs * 128 + 128; ++i) p += q[i] * W[(size_t)i * HH + j];
  lds[tid] = p;
  __syncthreads();
  if (tid < 64) out[blockIdx.x * 64 + tid] = lds[tid] + lds[tid + 64] + lds[tid + 128] + lds[tid + 192];
}

__launch_bounds__(512)
__global__ void k_attnT(const ushort* __restrict__ featT, const float* __restrict__ b2,
                        const float* __restrict__ av, const int* __restrict__ sel,
                        const float* __restrict__ gum, float* __restrict__ sc,
                        float* __restrict__ bZa, ull* __restrict__ bkey) {
  __shared__ float spart[8][128];
  const int tid = threadIdx.x, g = blockIdx.x;
  const int w = tid >> 6, lane = tid & 63;
  const int mb = g * 128 + lane * 2;
  const int h0 = w * 64;
  const ushort* fp = featT + (size_t)h0 * NP + mb;
  float acc0 = 0.f, acc1 = 0.f;
#pragma unroll 8
  for (int hh = 0; hh < 64; ++hh) {
    const unsigned u = *(const unsigned*)fp;
    fp += NP;
    const float bb = b2[h0 + hh], vv = av[h0 + hh];
    acc0 += ftanh(bflo(u) + bb) * vv;
    acc1 += ftanh(bfhi(u) + bb) * vv;
  }
  spart[w][lane * 2] = acc0;
  spart[w][lane * 2 + 1] = acc1;
  __syncthreads();
  if (w < 2) {
    const int idx = w * 64 + lane;
    const int m = g * 128 + idx;
    float s = 0.f;
#pragma unroll
    for (int w2 = 0; w2 < 8; ++w2) s += spart[w2][idx];
    const bool valid = (m < NROWS);
    float Z;
    ull key;
    if (valid) {
      float se = sel[m] ? NEGV : s;
      sc[m] = se;
      key = ((ull)fkey(se + gum[m]) << 32) | (unsigned)(NITEMS - m);
      Z = fexp(se);
    } else {
      key = 0;
      Z = 0.f;
    }
#pragma unroll
    for (int off = 32; off > 0; off >>= 1) {
      Z += __shfl_xor(Z, off);
      ull Ko = __shfl_xor(key, off);
      if (Ko > key) key = Ko;
    }
    if (lane == 0) { bZa[g * 2 + w] = Z; bkey[g * 2 + w] = key; }
  }
}

__launch_bounds__(256)
__global__ void k_tail(const float* __restrict__ bZa, const ull* __restrict__ bkey,
                       const float* __restrict__ sc, const int* __restrict__ done2,
                       float* __restrict__ outf) {
  __shared__ float redz[256];
  __shared__ ull redk[256];
  const int tid = threadIdx.x;
  float Zl = 0.f;
  ull Kl = 0;
  for (int i = tid; i < NGRP; i += 256) {
    Zl += bZa[i];
    ull k = bkey[i];
    if (k > Kl) Kl = k;
  }
  redz[tid] = Zl;
  redk[tid] = Kl;
  __syncthreads();
  for (int s2 = 128; s2 > 0; s2 >>= 1) {
    if (tid < s2) {
      redz[tid] += redz[tid + s2];
      if (redk[tid + s2] > redk[tid]) redk[tid] = redk[tid + s2];
    }
    __syncthreads();
  }
  if (tid == 0) {
    const float Z = redz[0];
    const ull K = redk[0];
    const int out = NITEMS - (int)(unsigned)(K & 0xffffffffull);
    const int d_in = done2[(TT - 1) & 1];
    outf[TT - 1] = (float)(d_in ? NITEMS : out);
    outf[2 * TT - 1] = d_in ? 0.f : (sc[out] - logf(Z));
  }
}

// ======================================================================
extern "C" void kernel_launch(void* const* d_in, const int* in_sizes, int n_in,
                              void* d_out, int out_size, void* d_ws, size_t ws_size,
                              hipStream_t stream) {
  const float* attn_mem = (const float*)d_in[0];
  const float* stoprow  = (const float*)d_in[1];
  const float* init_h   = (const float*)d_in[2];
  const float* init_c   = (const float*)d_in[3];
  const float* init_i   = (const float*)d_in[4];
  const float* attn_wm  = (const float*)d_in[5];
  const float* attn_wq  = (const float*)d_in[6];
  const float* attn_v   = (const float*)d_in[7];
  const float* hop_wm   = (const float*)d_in[8];
  const float* hop_wq   = (const float*)d_in[9];
  const float* hop_v    = (const float*)d_in[10];
  const float* w_ih     = (const float*)d_in[11];
  const float* w_hh     = (const float*)d_in[12];
  const float* b_ih     = (const float*)d_in[13];
  const float* b_hh     = (const float*)d_in[14];
  const float* gumbel   = (const float*)d_in[15];

  float* ws = (float*)d_ws;
  size_t fo = 0;
  const size_t FB = (size_t)NP * 512 / 2;
  ushort* hop_feat   = (ushort*)(ws + fo); fo += FB;
  ushort* attn_featT = (ushort*)(ws + fo); fo += FB;
  ushort* Ahi = (ushort*)(ws + fo); fo += FB;
  ushort* Alo = (ushort*)(ws + fo); fo += FB;
  ushort* WhiT_a = (ushort*)(ws + fo); fo += 131072;
  ushort* WloT_a = (ushort*)(ws + fo); fo += 131072;
  ushort* WhiT_h = (ushort*)(ws + fo); fo += 131072;
  ushort* WloT_h = (ushort*)(ws + fo); fo += 131072;
  float* sc  = ws + fo; fo += 50048;
  int* sel   = (int*)(ws + fo); fo += 50048;
  float* qp  = ws + fo; fo += (size_t)HOPBLK * 512;
  float* bZh = ws + fo; fo += HOPBLK;
  float* bZa = ws + fo; fo += 1024;
  ull* bkey  = (ull*)(ws + fo); fo += 2048;
  float* gates = ws + fo; fo += 4 * HH;
  float* hv  = ws + fo; fo += HH;
  float* cv0 = ws + fo; fo += HH;
  float* cv1 = ws + fo; fo += HH;
  float* b1  = ws + fo; fo += HH;
  float* b2  = ws + fo; fo += HH;
  float* qn  = ws + fo; fo += HH;
  int* done2 = (int*)(ws + fo); fo += 2;
  int* xrow2 = (int*)(ws + fo); fo += 2;
  if (fo * sizeof(float) > ws_size) return;

  float* outf = (float*)d_out;

  k_convA<<<(NP * 512 / 8) / 256, 256, 0, stream>>>(attn_mem, stoprow, Ahi, Alo);
  k_convBT<<<512, 256, 0, stream>>>(attn_wm, WhiT_a, WloT_a);
  k_convBT<<<512, 256, 0, stream>>>(hop_wm, WhiT_h, WloT_h);

  dim3 ggrid(4, NP / 128);
  k_mfma<1><<<ggrid, 256, 0, stream>>>(Ahi, Alo, WhiT_a, WloT_a, attn_featT);
  k_mfma<0><<<ggrid, 256, 0, stream>>>(Ahi, Alo, WhiT_h, WloT_h, hop_feat);

  P prm;
  prm.attn_mem = attn_mem; prm.stoprow = stoprow;
  prm.init_h = init_h; prm.init_c = init_c; prm.init_i = init_i;
  prm.attn_wq = attn_wq; prm.attn_v = attn_v;
  prm.hop_wq = hop_wq; prm.hop_v = hop_v;
  prm.w_ih = w_ih; prm.w_hh = w_hh; prm.b_ih = b_ih; prm.b_hh = b_hh;
  prm.gumbel = gumbel;
  prm.attn_featT = attn_featT; prm.hop_feat = hop_feat;
  prm.sc = sc; prm.sel = sel;
  prm.qp = qp; prm.bZh = bZh; prm.bZa = bZa; prm.bkey = bkey;
  prm.gates = gates; prm.hv = hv; prm.cv0 = cv0; prm.cv1 = cv1;
  prm.b1 = b1; prm.b2 = b2;
  prm.done2 = done2; prm.xrow2 = xrow2;
  prm.outf = outf;

  void* args[] = {&prm};
  hipError_t err = hipLaunchCooperativeKernel((void*)k_loop, dim3(NBC), dim3(NTC), args, 0, stream);

  if (err != hipSuccess) {
    // -------- discrete fallback (verified R9/R10 path) --------
    k_zero<<<196, 256, 0, stream>>>(sel);
    for (int t = 0; t < TT; ++t) {
      k_final_gates<<<512, 256, 0, stream>>>(bZa, bkey, sc, sel, done2, xrow2, outf,
                                             attn_mem, stoprow, init_i, init_h, hv,
                                             w_ih, w_hh, b_ih, b_hh, gates, t);
      k_hc_b1<<<8, 256, 0, stream>>>(gates, init_c, cv0, cv1, hv, hop_wq, b1, t);
      k_hop<<<HOPBLK, 256, 0, stream>>>(hop_feat, b1, hop_v, qp, bZh);
      k_qn<<<16, 1024, 0, stream>>>(qp, bZh, qn);
      k_gemv<<<8, 256, 0, stream>>>(qn, attn_wq, b2);
      k_attnT<<<(NP / 128), 512, 0, stream>>>(attn_featT, b2, attn_v, sel,
                                              gumbel + (size_t)t * NROWS, sc, bZa, bkey);
    }
    k_tail<<<1, 256, 0, stream>>>(bZa, bkey, sc, done2, outf);
  }
}

// Round 12
// 2088.978 us; speedup vs baseline: 2.4181x; 2.4181x over previous
//
#include <hip/hip_runtime.h>
#include <math.h>

#define NITEMS 50000
#define NROWS 50001
#define NP 50048          // padded row count (391*128)
#define DD 512
#define HH 512
#define TT 16
#define NEGV (-1e18f)
#define NGRP 782          // 391 groups x 2 partials
#define HOPB 512          // B grid blocks (x16 waves = 8192 waves)

typedef unsigned long long ull;
typedef unsigned short ushort;
typedef short short8 __attribute__((ext_vector_type(8)));
typedef float f32x4 __attribute__((ext_vector_type(4)));

__device__ __forceinline__ unsigned fkey(float f) {
  unsigned u = __float_as_uint(f);
  return (u & 0x80000000u) ? ~u : (u | 0x80000000u);
}
__device__ __forceinline__ float ftanh(float x) {
  float e = __builtin_amdgcn_exp2f(x * 2.885390081777927f);
  return 1.f - 2.f * __builtin_amdgcn_rcpf(e + 1.f);
}
__device__ __forceinline__ float fexp(float x) {
  return __builtin_amdgcn_exp2f(x * 1.4426950408889634f);
}
__device__ __forceinline__ ushort rne1(float a) {
  unsigned u = __float_as_uint(a);
  return (ushort)((u + 0x7fffu + ((u >> 16) & 1u)) >> 16);
}
__device__ __forceinline__ float bf2f(ushort h) { return __uint_as_float((unsigned)h << 16); }
__device__ __forceinline__ unsigned pack_bf16(float a, float b) {
  return (unsigned)rne1(a) | ((unsigned)rne1(b) << 16);
}
__device__ __forceinline__ float bflo(unsigned u) { return __uint_as_float(u << 16); }
__device__ __forceinline__ float bfhi(unsigned u) { return __uint_as_float(u & 0xffff0000u); }

__device__ __forceinline__ void gl_lds16(const void* g, void* l) {
#if __has_builtin(__builtin_amdgcn_global_load_lds)
  __builtin_amdgcn_global_load_lds((const __attribute__((address_space(1))) unsigned*)g,
                                   (__attribute__((address_space(3))) unsigned*)l, 16, 0, 0);
#else
  const int lane = threadIdx.x & 63;
  *(uint4*)((char*)l + lane * 16) = *(const uint4*)g;
#endif
}

#define MFMA(a, b, c) __builtin_amdgcn_mfma_f32_16x16x32_bf16(a, b, c, 0, 0, 0)

// ---------------- A -> (Ahi, Alo) bf16 [NP][512] ----------------
__global__ void k_convA(const float* __restrict__ A0, const float* __restrict__ stoprow,
                        ushort* __restrict__ Ahi, ushort* __restrict__ Alo) {
  const size_t t = (size_t)blockIdx.x * 256 + threadIdx.x;
  const size_t base = t * 8;
  const int row = (int)(base >> 9);
  float v[8];
  if (row < NITEMS) {
    const float4* p = (const float4*)(A0 + base);
    float4 x = p[0], y = p[1];
    v[0] = x.x; v[1] = x.y; v[2] = x.z; v[3] = x.w;
    v[4] = y.x; v[5] = y.y; v[6] = y.z; v[7] = y.w;
  } else if (row == NITEMS) {
    const float4* p = (const float4*)(stoprow + (base & 511));
    float4 x = p[0], y = p[1];
    v[0] = x.x; v[1] = x.y; v[2] = x.z; v[3] = x.w;
    v[4] = y.x; v[5] = y.y; v[6] = y.z; v[7] = y.w;
  } else {
#pragma unroll
    for (int j = 0; j < 8; ++j) v[j] = 0.f;
  }
  unsigned hw[4], lw[4];
#pragma unroll
  for (int j = 0; j < 4; ++j) {
    float a0 = v[2 * j], a1 = v[2 * j + 1];
    ushort h0 = rne1(a0), h1 = rne1(a1);
    hw[j] = (unsigned)h0 | ((unsigned)h1 << 16);
    lw[j] = pack_bf16(a0 - bf2f(h0), a1 - bf2f(h1));
  }
  *(uint4*)(Ahi + base) = make_uint4(hw[0], hw[1], hw[2], hw[3]);
  *(uint4*)(Alo + base) = make_uint4(lw[0], lw[1], lw[2], lw[3]);
}

// ---------------- W [k][n] -> transposed bf16 ----------------
__global__ void k_convBT(const float* __restrict__ W, ushort* __restrict__ WhiT,
                         ushort* __restrict__ WloT) {
  const int n = blockIdx.x;
  const int k0 = threadIdx.x * 2;
  float a0 = W[(size_t)k0 * 512 + n];
  float a1 = W[(size_t)(k0 + 1) * 512 + n];
  ushort h0 = rne1(a0), h1 = rne1(a1);
  *(unsigned*)(WhiT + (size_t)n * 512 + k0) = (unsigned)h0 | ((unsigned)h1 << 16);
  *(unsigned*)(WloT + (size_t)n * 512 + k0) = pack_bf16(a0 - bf2f(h0), a1 - bf2f(h1));
}

// ---------------- MFMA GEMM (verified R10) ----------------
template <int TR>
__launch_bounds__(256, 2)
__global__ void k_mfma(const ushort* __restrict__ Ahi, const ushort* __restrict__ Alo,
                       const ushort* __restrict__ BhT, const ushort* __restrict__ BlT,
                       ushort* __restrict__ C) {
  __shared__ __align__(16) char lds[65536];
  char* sA0 = lds;
  char* sA1 = lds + 16384;
  char* sB0 = lds + 32768;
  char* sB1 = lds + 49152;
  const int tid = threadIdx.x;
  const int lane = tid & 63, w = tid >> 6;
  const int lid = blockIdx.y * 4 + blockIdx.x;
  const int xcd = lid & 7, pos = lid >> 3;
  const int orig = ((xcd < 4) ? xcd * 196 : 784 + (xcd - 4) * 195) + pos;
  const int m0 = (orig >> 2) * 128, n0 = (orig & 3) * 128;
  const int aR0 = (w & 1) * 64, bR0 = (w >> 1) * 64;

  f32x4 acc[4][4];
  const f32x4 z4 = {0.f, 0.f, 0.f, 0.f};
#pragma unroll
  for (int i = 0; i < 4; ++i)
#pragma unroll
    for (int j = 0; j < 4; ++j) acc[i][j] = z4;

#define STAGE_ALL(KT)                                                                     \
  {                                                                                       \
    _Pragma("unroll") for (int i = 0; i < 4; ++i) {                                       \
      const int row = i * 32 + (tid >> 3);                                                \
      const int kb = ((tid & 7) << 4) ^ ((row & 7) << 4);                                 \
      const int ldso = i * 4096 + (w << 10);                                              \
      gl_lds16((const char*)(Ahi + ((size_t)(m0 + row) << 9) + (KT)) + kb, sA0 + ldso);   \
      gl_lds16((const char*)(Alo + ((size_t)(m0 + row) << 9) + (KT)) + kb, sA1 + ldso);   \
      gl_lds16((const char*)(BhT + ((size_t)(n0 + row) << 9) + (KT)) + kb, sB0 + ldso);   \
      gl_lds16((const char*)(BlT + ((size_t)(n0 + row) << 9) + (KT)) + kb, sB1 + ldso);   \
    }                                                                                     \
  }

  STAGE_ALL(0)
  __syncthreads();
  for (int c = 0; c < 8; ++c) {
#pragma unroll
    for (int ks = 0; ks < 2; ++ks) {
      short8 ah[4], al[4], bh[4], bl[4];
      const int kbb = ks * 64 + ((lane >> 4) << 4);
#pragma unroll
      for (int f = 0; f < 4; ++f) {
        const int ra = aR0 + f * 16 + (lane & 15);
        const int oa = ra * 128 + (kbb ^ ((ra & 7) << 4));
        ah[f] = *(const short8*)(sA0 + oa);
        al[f] = *(const short8*)(sA1 + oa);
        const int rb = bR0 + f * 16 + (lane & 15);
        const int ob = rb * 128 + (kbb ^ ((rb & 7) << 4));
        bh[f] = *(const short8*)(sB0 + ob);
        bl[f] = *(const short8*)(sB1 + ob);
      }
#pragma unroll
      for (int mf = 0; mf < 4; ++mf)
#pragma unroll
        for (int nf = 0; nf < 4; ++nf) {
          acc[mf][nf] = MFMA(ah[mf], bh[nf], acc[mf][nf]);
          acc[mf][nf] = MFMA(ah[mf], bl[nf], acc[mf][nf]);
          acc[mf][nf] = MFMA(al[mf], bh[nf], acc[mf][nf]);
        }
    }
    if (c < 7) {
      __syncthreads();
      STAGE_ALL((c + 1) * 64)
      __syncthreads();
    }
  }
#undef STAGE_ALL

#pragma unroll
  for (int mf = 0; mf < 4; ++mf)
#pragma unroll
    for (int nf = 0; nf < 4; ++nf) {
      const f32x4 a = acc[mf][nf];
      const int n = n0 + bR0 + nf * 16 + (lane & 15);
      const int mb = m0 + aR0 + mf * 16 + ((lane >> 4) << 2);
      if (TR) {
        ushort* p = C + (size_t)n * NP + mb;
        *(uint2*)p = make_uint2(pack_bf16(a.x, a.y), pack_bf16(a.z, a.w));
      } else {
        C[(size_t)(mb + 0) * 512 + n] = rne1(a.x);
        C[(size_t)(mb + 1) * 512 + n] = rne1(a.y);
        C[(size_t)(mb + 2) * 512 + n] = rne1(a.z);
        C[(size_t)(mb + 3) * 512 + n] = rne1(a.w);
      }
    }
}

// ---------------- zero sel + counters ----------------
__global__ void k_zero(int* __restrict__ sel, unsigned* __restrict__ cnts) {
  int i = blockIdx.x * 256 + threadIdx.x;
  if (i < NROWS) sel[i] = 0;
  if (blockIdx.x == 0 && threadIdx.x < 16) cnts[threadIdx.x] = 0;
}

// ================= A: LSTM gates (unit-remapped) + h,c; last block: b1 = h @ hop_wq =================
__launch_bounds__(256)
__global__ void k_A(const float* __restrict__ attn_mem, const float* __restrict__ stoprow,
                    const float* __restrict__ init_i, const float* __restrict__ init_h,
                    const float* __restrict__ init_c,
                    const float* __restrict__ w_ih, const float* __restrict__ w_hh,
                    const float* __restrict__ b_ih, const float* __restrict__ b_hh,
                    const float* __restrict__ hop_wq,
                    float* __restrict__ hv0, float* __restrict__ hv1,
                    float* __restrict__ cv0, float* __restrict__ cv1,
                    float* __restrict__ b1, const int* __restrict__ xrow_buf,
                    unsigned* __restrict__ cntA, int t) {
  __shared__ float g4[4];
  __shared__ float hs[512];
  __shared__ int isLast;
  const int b = blockIdx.x, tid = threadIdx.x, w = tid >> 6, lane = tid & 63;
  const int xrow = (t == 0) ? -1 : *xrow_buf;
  const float* xp = (xrow < 0) ? init_i
                               : ((xrow == NITEMS) ? stoprow : attn_mem + (size_t)xrow * DD);
  const float* hsrc = (t == 0) ? init_h : ((t & 1) ? hv0 : hv1);
  float* hdst = (t & 1) ? hv1 : hv0;
  const float* csrc = (t == 0) ? init_c : ((t & 1) ? cv0 : cv1);
  float* cdst = (t & 1) ? cv1 : cv0;

  const int r = w * 512 + b;  // gate section w, unit b
  const float4* x4 = (const float4*)xp;
  const float4* h4 = (const float4*)hsrc;
  const float4* wi = (const float4*)(w_ih + (size_t)r * DD);
  const float4* wh = (const float4*)(w_hh + (size_t)r * DD);
  float s = 0.f;
  float4 a, ww;
  a = x4[lane * 2];     ww = wi[lane * 2];     s += a.x * ww.x + a.y * ww.y + a.z * ww.z + a.w * ww.w;
  a = x4[lane * 2 + 1]; ww = wi[lane * 2 + 1]; s += a.x * ww.x + a.y * ww.y + a.z * ww.z + a.w * ww.w;
  a = h4[lane * 2];     ww = wh[lane * 2];     s += a.x * ww.x + a.y * ww.y + a.z * ww.z + a.w * ww.w;
  a = h4[lane * 2 + 1]; ww = wh[lane * 2 + 1]; s += a.x * ww.x + a.y * ww.y + a.z * ww.z + a.w * ww.w;
#pragma unroll
  for (int off = 32; off > 0; off >>= 1) s += __shfl_xor(s, off);
  if (lane == 0) g4[w] = s + b_ih[r] + b_hh[r];
  __syncthreads();
  if (tid == 0) {
    const float si = 1.f / (1.f + expf(-g4[0]));
    const float sf = 1.f / (1.f + expf(-g4[1]));
    const float so = 1.f / (1.f + expf(-g4[3]));
    const float cn = sf * csrc[b] + si * tanhf(g4[2]);
    cdst[b] = cn;
    hdst[b] = so * tanhf(cn);
  }
  __syncthreads();
  if (tid == 0) {
    __threadfence();
    unsigned old = atomicAdd(cntA, 1u);
    isLast = (old == gridDim.x - 1);
    if (isLast) *cntA = 0;
  }
  __syncthreads();
  if (isLast) {
    __threadfence();
    hs[tid] = hdst[tid];
    hs[tid + 256] = hdst[tid + 256];
    __syncthreads();
    float a0 = 0.f, a1 = 0.f;
    for (int i = 0; i < 512; ++i) {
      const float hvv = hs[i];
      const float* wr = hop_wq + (size_t)i * 512;
      a0 = fmaf(hvv, wr[tid], a0);
      a1 = fmaf(hvv, wr[tid + 256], a1);
    }
    b1[tid] = a0;
    b1[tid + 256] = a1;
  }
}

// ================= B: hop sweep; last block: Z + qn + b2 = qn @ attn_wq =================
__launch_bounds__(1024)
__global__ void k_B(const ushort* __restrict__ feat, const float* __restrict__ b1,
                    const float* __restrict__ hop_v, const float* __restrict__ attn_wq,
                    float* __restrict__ qp, float* __restrict__ bZh, float* __restrict__ b2,
                    unsigned* __restrict__ cntB) {
  __shared__ float qbuf[16][512];
  __shared__ float sz[16];
  __shared__ float red[1024];
  __shared__ float qns[512];
  __shared__ int isLast;
  const int tid = threadIdx.x, blk = blockIdx.x;
  const int w = tid >> 6, lane = tid & 63;
  float bv[8], vv[8], qa[8];
#pragma unroll
  for (int j = 0; j < 8; ++j) { bv[j] = b1[lane * 8 + j]; vv[j] = hop_v[lane * 8 + j]; qa[j] = 0.f; }
  float Z = 0.f;
  const int wv = blk * 16 + w;
  for (int m = wv; m < NROWS; m += 16 * HOPB) {
    const uint4 U = ((const uint4*)(feat + (size_t)m * HH))[lane];
    float f[8] = {bflo(U.x), bfhi(U.x), bflo(U.y), bfhi(U.y),
                  bflo(U.z), bfhi(U.z), bflo(U.w), bfhi(U.w)};
    float s = 0.f;
#pragma unroll
    for (int j = 0; j < 8; ++j) s += ftanh(f[j] + bv[j]) * vv[j];
#pragma unroll
    for (int off = 32; off > 0; off >>= 1) s += __shfl_xor(s, off);
    const float e = fexp(s);
    Z += e;
#pragma unroll
    for (int j = 0; j < 8; ++j) qa[j] = fmaf(e, f[j], qa[j]);
  }
  if (lane == 0) sz[w] = Z;
#pragma unroll
  for (int j = 0; j < 8; ++j) qbuf[w][lane * 8 + j] = qa[j];
  __syncthreads();
  {
    const int col = tid & 511, half = tid >> 9;
    float a = 0.f;
#pragma unroll
    for (int w2 = half * 8; w2 < half * 8 + 8; ++w2) a += qbuf[w2][col];
    red[tid] = a;
  }
  __syncthreads();
  if (tid < 512) qp[(size_t)blk * 512 + tid] = red[tid] + red[tid + 512];
  if (tid == 0) {
    float z = 0.f;
#pragma unroll
    for (int w2 = 0; w2 < 16; ++w2) z += sz[w2];
    bZh[blk] = z;
  }
  __syncthreads();
  if (tid == 0) {
    __threadfence();
    unsigned old = atomicAdd(cntB, 1u);
    isLast = (old == gridDim.x - 1);
    if (isLast) *cntB = 0;
  }
  __syncthreads();
  if (isLast) {
    __threadfence();
    red[tid] = (tid < HOPB) ? bZh[tid] : 0.f;
    __syncthreads();
    for (int s2 = 512; s2 > 0; s2 >>= 1) {
      if (tid < s2) red[tid] += red[tid + s2];
      __syncthreads();
    }
    const float Zt = red[0];
    __syncthreads();
    {
      const int col = tid & 511, half = tid >> 9;
      float a = 0.f;
      for (int p = half * 256; p < half * 256 + 256; ++p) a += qp[(size_t)p * 512 + col];
      red[tid] = a;
    }
    __syncthreads();
    if (tid < 512) qns[tid] = (red[tid] + red[tid + 512]) / Zt;
    __syncthreads();
    {
      const int j = tid & 511, seg = tid >> 9;
      float a = 0.f;
      for (int i = seg * 256; i < seg * 256 + 256; ++i)
        a = fmaf(qns[i], attn_wq[(size_t)i * 512 + j], a);
      red[tid] = a;
    }
    __syncthreads();
    if (tid < 512) b2[tid] = red[tid] + red[tid + 512];
  }
}

// ================= C: attn transposed sweep; last block: sample + bookkeeping + outputs =================
__launch_bounds__(512)
__global__ void k_C(const ushort* __restrict__ featT, const float* __restrict__ b2,
                    const float* __restrict__ av, int* __restrict__ sel,
                    const float* __restrict__ gum, float* __restrict__ sc,
                    float* __restrict__ bZa, ull* __restrict__ bkey,
                    int* __restrict__ done_buf, int* __restrict__ xrow_buf,
                    float* __restrict__ outf, unsigned* __restrict__ cntC, int t) {
  __shared__ float spart[8][128];
  __shared__ float rz[512];
  __shared__ ull rk[512];
  __shared__ int isLast;
  const int tid = threadIdx.x, g = blockIdx.x;
  const int w = tid >> 6, lane = tid & 63;
  const int mb = g * 128 + lane * 2;
  const int h0 = w * 64;
  const ushort* fp = featT + (size_t)h0 * NP + mb;
  float acc0 = 0.f, acc1 = 0.f;
#pragma unroll 8
  for (int hh = 0; hh < 64; ++hh) {
    const unsigned u = *(const unsigned*)fp;
    fp += NP;
    const float bb = b2[h0 + hh], vv = av[h0 + hh];
    acc0 += ftanh(bflo(u) + bb) * vv;
    acc1 += ftanh(bfhi(u) + bb) * vv;
  }
  spart[w][lane * 2] = acc0;
  spart[w][lane * 2 + 1] = acc1;
  __syncthreads();
  if (w < 2) {
    const int idx = w * 64 + lane;
    const int m = g * 128 + idx;
    float s = 0.f;
#pragma unroll
    for (int w2 = 0; w2 < 8; ++w2) s += spart[w2][idx];
    const bool valid = (m < NROWS);
    float Z;
    ull key;
    if (valid) {
      float se = sel[m] ? NEGV : s;
      sc[m] = se;
      key = ((ull)fkey(se + gum[m]) << 32) | (unsigned)(NITEMS - m);
      Z = fexp(se);
    } else {
      key = 0;
      Z = 0.f;
    }
#pragma unroll
    for (int off = 32; off > 0; off >>= 1) {
      Z += __shfl_xor(Z, off);
      ull Ko = __shfl_xor(key, off);
      if (Ko > key) key = Ko;
    }
    if (lane == 0) { bZa[g * 2 + w] = Z; bkey[g * 2 + w] = key; }
  }
  __syncthreads();
  if (tid == 0) {
    __threadfence();
    unsigned old = atomicAdd(cntC, 1u);
    isLast = (old == gridDim.x - 1);
    if (isLast) *cntC = 0;
  }
  __syncthreads();
  if (isLast) {
    __threadfence();
    float Zl = 0.f;
    ull Kl = 0;
    for (int i = tid; i < NGRP; i += 512) {
      Zl += bZa[i];
      ull k = bkey[i];
      if (k > Kl) Kl = k;
    }
    rz[tid] = Zl;
    rk[tid] = Kl;
    __syncthreads();
    for (int s2 = 256; s2 > 0; s2 >>= 1) {
      if (tid < s2) {
        rz[tid] += rz[tid + s2];
        if (rk[tid + s2] > rk[tid]) rk[tid] = rk[tid + s2];
      }
      __syncthreads();
    }
    if (tid == 0) {
      const float Z = rz[0];
      const ull K = rk[0];
      const int out = NITEMS - (int)(unsigned)(K & 0xffffffffull);
      const int d_in = (t == 0) ? 0 : *done_buf;
      const int xprev = (t == 0) ? -1 : *xrow_buf;
      const int nd = d_in | (out == NITEMS);
      outf[t] = (float)(d_in ? NITEMS : out);
      outf[TT + t] = d_in ? 0.f : (sc[out] - logf(Z));
      if (!d_in) sel[out] = 1;
      *done_buf = nd;
      *xrow_buf = nd ? xprev : out;
    }
  }
}

// ======================================================================
extern "C" void kernel_launch(void* const* d_in, const int* in_sizes, int n_in,
                              void* d_out, int out_size, void* d_ws, size_t ws_size,
                              hipStream_t stream) {
  const float* attn_mem = (const float*)d_in[0];
  const float* stoprow  = (const float*)d_in[1];
  const float* init_h   = (const float*)d_in[2];
  const float* init_c   = (const float*)d_in[3];
  const float* init_i   = (const float*)d_in[4];
  const float* attn_wm  = (const float*)d_in[5];
  const float* attn_wq  = (const float*)d_in[6];
  const float* attn_v   = (const float*)d_in[7];
  const float* hop_wm   = (const float*)d_in[8];
  const float* hop_wq   = (const float*)d_in[9];
  const float* hop_v    = (const float*)d_in[10];
  const float* w_ih     = (const float*)d_in[11];
  const float* w_hh     = (const float*)d_in[12];
  const float* b_ih     = (const float*)d_in[13];
  const float* b_hh     = (const float*)d_in[14];
  const float* gumbel   = (const float*)d_in[15];

  float* ws = (float*)d_ws;
  size_t fo = 0;
  const size_t FB = (size_t)NP * 512 / 2;
  ushort* hop_feat   = (ushort*)(ws + fo); fo += FB;
  ushort* attn_featT = (ushort*)(ws + fo); fo += FB;
  ushort* Ahi = (ushort*)(ws + fo); fo += FB;
  ushort* Alo = (ushort*)(ws + fo); fo += FB;
  ushort* WhiT_a = (ushort*)(ws + fo); fo += 131072;
  ushort* WloT_a = (ushort*)(ws + fo); fo += 131072;
  ushort* WhiT_h = (ushort*)(ws + fo); fo += 131072;
  ushort* WloT_h = (ushort*)(ws + fo); fo += 131072;
  float* sc  = ws + fo; fo += 50048;
  int* sel   = (int*)(ws + fo); fo += 50048;
  float* qp  = ws + fo; fo += (size_t)HOPB * 512;
  float* bZh = ws + fo; fo += HOPB;
  float* bZa = ws + fo; fo += 1024;
  ull* bkey  = (ull*)(ws + fo); fo += 2048;
  float* hv0 = ws + fo; fo += HH;
  float* hv1 = ws + fo; fo += HH;
  float* cv0 = ws + fo; fo += HH;
  float* cv1 = ws + fo; fo += HH;
  float* b1  = ws + fo; fo += HH;
  float* b2  = ws + fo; fo += HH;
  unsigned* cnts = (unsigned*)(ws + fo); fo += 16;
  int* done_buf = (int*)(ws + fo); fo += 2;
  int* xrow_buf = (int*)(ws + fo); fo += 2;
  if (fo * sizeof(float) > ws_size) return;

  float* outf = (float*)d_out;

  k_zero<<<196, 256, 0, stream>>>(sel, cnts);
  k_convA<<<(NP * 512 / 8) / 256, 256, 0, stream>>>(attn_mem, stoprow, Ahi, Alo);
  k_convBT<<<512, 256, 0, stream>>>(attn_wm, WhiT_a, WloT_a);
  k_convBT<<<512, 256, 0, stream>>>(hop_wm, WhiT_h, WloT_h);

  dim3 ggrid(4, NP / 128);
  k_mfma<1><<<ggrid, 256, 0, stream>>>(Ahi, Alo, WhiT_a, WloT_a, attn_featT);
  k_mfma<0><<<ggrid, 256, 0, stream>>>(Ahi, Alo, WhiT_h, WloT_h, hop_feat);

  for (int t = 0; t < TT; ++t) {
    k_A<<<512, 256, 0, stream>>>(attn_mem, stoprow, init_i, init_h, init_c,
                                 w_ih, w_hh, b_ih, b_hh, hop_wq,
                                 hv0, hv1, cv0, cv1, b1, xrow_buf, cnts + 0, t);
    k_B<<<HOPB, 1024, 0, stream>>>(hop_feat, b1, hop_v, attn_wq, qp, bZh, b2, cnts + 1);
    k_C<<<NP / 128, 512, 0, stream>>>(attn_featT, b2, attn_v, sel,
                                      gumbel + (size_t)t * NROWS, sc, bZa, bkey,
                                      done_buf, xrow_buf, outf, cnts + 2, t);
  }
}

// Round 13
// 1932.546 us; speedup vs baseline: 2.6139x; 1.0809x over previous
//
#include <hip/hip_runtime.h>
#include <math.h>

#define NITEMS 50000
#define NROWS 50001
#define NP 50176          // padded row count (392*128 = 196*256)
#define DD 512
#define HH 512
#define TT 16
#define NEGV (-1e18f)
#define NGRP 784          // 196 blocks x 4 partials
#define NGC 196           // k_C blocks (256 rows each)
#define HOPB 512          // k_B grid (x16 waves = 8192 waves)

typedef unsigned long long ull;
typedef unsigned short ushort;
typedef short short8 __attribute__((ext_vector_type(8)));
typedef float f32x4 __attribute__((ext_vector_type(4)));

__device__ __forceinline__ unsigned fkey(float f) {
  unsigned u = __float_as_uint(f);
  return (u & 0x80000000u) ? ~u : (u | 0x80000000u);
}
__device__ __forceinline__ float ftanh(float x) {
  float e = __builtin_amdgcn_exp2f(x * 2.885390081777927f);
  return 1.f - 2.f * __builtin_amdgcn_rcpf(e + 1.f);
}
__device__ __forceinline__ float fexp(float x) {
  return __builtin_amdgcn_exp2f(x * 1.4426950408889634f);
}
__device__ __forceinline__ ushort rne1(float a) {
  unsigned u = __float_as_uint(a);
  return (ushort)((u + 0x7fffu + ((u >> 16) & 1u)) >> 16);
}
__device__ __forceinline__ float bf2f(ushort h) { return __uint_as_float((unsigned)h << 16); }
__device__ __forceinline__ unsigned pack_bf16(float a, float b) {
  return (unsigned)rne1(a) | ((unsigned)rne1(b) << 16);
}
__device__ __forceinline__ float bflo(unsigned u) { return __uint_as_float(u << 16); }
__device__ __forceinline__ float bfhi(unsigned u) { return __uint_as_float(u & 0xffff0000u); }

__device__ __forceinline__ void gl_lds16(const void* g, void* l) {
#if __has_builtin(__builtin_amdgcn_global_load_lds)
  __builtin_amdgcn_global_load_lds((const __attribute__((address_space(1))) unsigned*)g,
                                   (__attribute__((address_space(3))) unsigned*)l, 16, 0, 0);
#else
  const int lane = threadIdx.x & 63;
  *(uint4*)((char*)l + lane * 16) = *(const uint4*)g;
#endif
}

#define MFMA(a, b, c) __builtin_amdgcn_mfma_f32_16x16x32_bf16(a, b, c, 0, 0, 0)

// ---------------- A -> (Ahi, Alo) bf16 [NP][512] ----------------
__global__ void k_convA(const float* __restrict__ A0, const float* __restrict__ stoprow,
                        ushort* __restrict__ Ahi, ushort* __restrict__ Alo) {
  const size_t t = (size_t)blockIdx.x * 256 + threadIdx.x;
  const size_t base = t * 8;
  const int row = (int)(base >> 9);
  float v[8];
  if (row < NITEMS) {
    const float4* p = (const float4*)(A0 + base);
    float4 x = p[0], y = p[1];
    v[0] = x.x; v[1] = x.y; v[2] = x.z; v[3] = x.w;
    v[4] = y.x; v[5] = y.y; v[6] = y.z; v[7] = y.w;
  } else if (row == NITEMS) {
    const float4* p = (const float4*)(stoprow + (base & 511));
    float4 x = p[0], y = p[1];
    v[0] = x.x; v[1] = x.y; v[2] = x.z; v[3] = x.w;
    v[4] = y.x; v[5] = y.y; v[6] = y.z; v[7] = y.w;
  } else {
#pragma unroll
    for (int j = 0; j < 8; ++j) v[j] = 0.f;
  }
  unsigned hw[4], lw[4];
#pragma unroll
  for (int j = 0; j < 4; ++j) {
    float a0 = v[2 * j], a1 = v[2 * j + 1];
    ushort h0 = rne1(a0), h1 = rne1(a1);
    hw[j] = (unsigned)h0 | ((unsigned)h1 << 16);
    lw[j] = pack_bf16(a0 - bf2f(h0), a1 - bf2f(h1));
  }
  *(uint4*)(Ahi + base) = make_uint4(hw[0], hw[1], hw[2], hw[3]);
  *(uint4*)(Alo + base) = make_uint4(lw[0], lw[1], lw[2], lw[3]);
}

// ---------------- W [k][n] -> transposed bf16 ----------------
__global__ void k_convBT(const float* __restrict__ W, ushort* __restrict__ WhiT,
                         ushort* __restrict__ WloT) {
  const int n = blockIdx.x;
  const int k0 = threadIdx.x * 2;
  float a0 = W[(size_t)k0 * 512 + n];
  float a1 = W[(size_t)(k0 + 1) * 512 + n];
  ushort h0 = rne1(a0), h1 = rne1(a1);
  *(unsigned*)(WhiT + (size_t)n * 512 + k0) = (unsigned)h0 | ((unsigned)h1 << 16);
  *(unsigned*)(WloT + (size_t)n * 512 + k0) = pack_bf16(a0 - bf2f(h0), a1 - bf2f(h1));
}

// ---------------- MFMA GEMM (verified R10; swizzle now exact: 1568 = 8*196) ----------------
template <int TR>
__launch_bounds__(256, 2)
__global__ void k_mfma(const ushort* __restrict__ Ahi, const ushort* __restrict__ Alo,
                       const ushort* __restrict__ BhT, const ushort* __restrict__ BlT,
                       ushort* __restrict__ C) {
  __shared__ __align__(16) char lds[65536];
  char* sA0 = lds;
  char* sA1 = lds + 16384;
  char* sB0 = lds + 32768;
  char* sB1 = lds + 49152;
  const int tid = threadIdx.x;
  const int lane = tid & 63, w = tid >> 6;
  const int lid = blockIdx.y * 4 + blockIdx.x;
  const int xcd = lid & 7, pos = lid >> 3;
  const int orig = xcd * 196 + pos;
  const int m0 = (orig >> 2) * 128, n0 = (orig & 3) * 128;
  const int aR0 = (w & 1) * 64, bR0 = (w >> 1) * 64;

  f32x4 acc[4][4];
  const f32x4 z4 = {0.f, 0.f, 0.f, 0.f};
#pragma unroll
  for (int i = 0; i < 4; ++i)
#pragma unroll
    for (int j = 0; j < 4; ++j) acc[i][j] = z4;

#define STAGE_ALL(KT)                                                                     \
  {                                                                                       \
    _Pragma("unroll") for (int i = 0; i < 4; ++i) {                                       \
      const int row = i * 32 + (tid >> 3);                                                \
      const int kb = ((tid & 7) << 4) ^ ((row & 7) << 4);                                 \
      const int ldso = i * 4096 + (w << 10);                                              \
      gl_lds16((const char*)(Ahi + ((size_t)(m0 + row) << 9) + (KT)) + kb, sA0 + ldso);   \
      gl_lds16((const char*)(Alo + ((size_t)(m0 + row) << 9) + (KT)) + kb, sA1 + ldso);   \
      gl_lds16((const char*)(BhT + ((size_t)(n0 + row) << 9) + (KT)) + kb, sB0 + ldso);   \
      gl_lds16((const char*)(BlT + ((size_t)(n0 + row) << 9) + (KT)) + kb, sB1 + ldso);   \
    }                                                                                     \
  }

  STAGE_ALL(0)
  __syncthreads();
  for (int c = 0; c < 8; ++c) {
#pragma unroll
    for (int ks = 0; ks < 2; ++ks) {
      short8 ah[4], al[4], bh[4], bl[4];
      const int kbb = ks * 64 + ((lane >> 4) << 4);
#pragma unroll
      for (int f = 0; f < 4; ++f) {
        const int ra = aR0 + f * 16 + (lane & 15);
        const int oa = ra * 128 + (kbb ^ ((ra & 7) << 4));
        ah[f] = *(const short8*)(sA0 + oa);
        al[f] = *(const short8*)(sA1 + oa);
        const int rb = bR0 + f * 16 + (lane & 15);
        const int ob = rb * 128 + (kbb ^ ((rb & 7) << 4));
        bh[f] = *(const short8*)(sB0 + ob);
        bl[f] = *(const short8*)(sB1 + ob);
      }
#pragma unroll
      for (int mf = 0; mf < 4; ++mf)
#pragma unroll
        for (int nf = 0; nf < 4; ++nf) {
          acc[mf][nf] = MFMA(ah[mf], bh[nf], acc[mf][nf]);
          acc[mf][nf] = MFMA(ah[mf], bl[nf], acc[mf][nf]);
          acc[mf][nf] = MFMA(al[mf], bh[nf], acc[mf][nf]);
        }
    }
    if (c < 7) {
      __syncthreads();
      STAGE_ALL((c + 1) * 64)
      __syncthreads();
    }
  }
#undef STAGE_ALL

#pragma unroll
  for (int mf = 0; mf < 4; ++mf)
#pragma unroll
    for (int nf = 0; nf < 4; ++nf) {
      const f32x4 a = acc[mf][nf];
      const int n = n0 + bR0 + nf * 16 + (lane & 15);
      const int mb = m0 + aR0 + mf * 16 + ((lane >> 4) << 2);
      if (TR) {
        ushort* p = C + (size_t)n * NP + mb;
        *(uint2*)p = make_uint2(pack_bf16(a.x, a.y), pack_bf16(a.z, a.w));
      } else {
        C[(size_t)(mb + 0) * 512 + n] = rne1(a.x);
        C[(size_t)(mb + 1) * 512 + n] = rne1(a.y);
        C[(size_t)(mb + 2) * 512 + n] = rne1(a.z);
        C[(size_t)(mb + 3) * 512 + n] = rne1(a.w);
      }
    }
}

// ---------------- zero sel + counters/flags ----------------
// cnts[0..3] = counters A,B,C,B2 ; cnts[16+t]=flagA ; cnts[32+t]=flagB ; cnts[48+t]=flagB2
__global__ void k_zero(int* __restrict__ sel, unsigned* __restrict__ cnts) {
  int i = blockIdx.x * 256 + threadIdx.x;
  if (i < NROWS) sel[i] = 0;
  if (blockIdx.x == 0 && threadIdx.x < 80) cnts[threadIdx.x] = 0;
}

// ================= A: LSTM gates + h,c; last-16 blocks: b1 slices =================
__launch_bounds__(256)
__global__ void k_A(const float* __restrict__ attn_mem, const float* __restrict__ stoprow,
                    const float* __restrict__ init_i, const float* __restrict__ init_h,
                    const float* __restrict__ init_c,
                    const float* __restrict__ w_ih, const float* __restrict__ w_hh,
                    const float* __restrict__ b_ih, const float* __restrict__ b_hh,
                    const float* __restrict__ hop_wq,
                    float* __restrict__ hv0, float* __restrict__ hv1,
                    float* __restrict__ cv0, float* __restrict__ cv1,
                    float* __restrict__ b1, const int* __restrict__ xrow_buf,
                    unsigned* __restrict__ cntA, unsigned* __restrict__ flagA, int t) {
  __shared__ float g4[4];
  __shared__ float hs[512];
  __shared__ float red2[256];
  __shared__ int sOld;
  const int b = blockIdx.x, tid = threadIdx.x, w = tid >> 6, lane = tid & 63;
  const int xrow = (t == 0) ? -1 : *xrow_buf;
  const float* xp = (xrow < 0) ? init_i
                               : ((xrow == NITEMS) ? stoprow : attn_mem + (size_t)xrow * DD);
  const float* hsrc = (t == 0) ? init_h : ((t & 1) ? hv0 : hv1);
  float* hdst = (t & 1) ? hv1 : hv0;
  const float* csrc = (t == 0) ? init_c : ((t & 1) ? cv0 : cv1);
  float* cdst = (t & 1) ? cv1 : cv0;

  const int r = w * 512 + b;  // gate section w, unit b
  const float4* x4 = (const float4*)xp;
  const float4* h4 = (const float4*)hsrc;
  const float4* wi = (const float4*)(w_ih + (size_t)r * DD);
  const float4* wh = (const float4*)(w_hh + (size_t)r * DD);
  float s = 0.f;
  float4 a, ww;
  a = x4[lane * 2];     ww = wi[lane * 2];     s += a.x * ww.x + a.y * ww.y + a.z * ww.z + a.w * ww.w;
  a = x4[lane * 2 + 1]; ww = wi[lane * 2 + 1]; s += a.x * ww.x + a.y * ww.y + a.z * ww.z + a.w * ww.w;
  a = h4[lane * 2];     ww = wh[lane * 2];     s += a.x * ww.x + a.y * ww.y + a.z * ww.z + a.w * ww.w;
  a = h4[lane * 2 + 1]; ww = wh[lane * 2 + 1]; s += a.x * ww.x + a.y * ww.y + a.z * ww.z + a.w * ww.w;
#pragma unroll
  for (int off = 32; off > 0; off >>= 1) s += __shfl_xor(s, off);
  if (lane == 0) g4[w] = s + b_ih[r] + b_hh[r];
  __syncthreads();
  if (tid == 0) {
    const float si = 1.f / (1.f + expf(-g4[0]));
    const float sf = 1.f / (1.f + expf(-g4[1]));
    const float so = 1.f / (1.f + expf(-g4[3]));
    const float cn = sf * csrc[b] + si * tanhf(g4[2]);
    cdst[b] = cn;
    hdst[b] = so * tanhf(cn);
  }
  __syncthreads();
  if (tid == 0) {
    __threadfence();
    unsigned old = atomicAdd(cntA, 1u);
    if (old == 511u) { atomicExch(flagA, 1u); *cntA = 0u; }
    sOld = (int)old;
  }
  __syncthreads();
  const int old = sOld;
  if (old >= 496) {
    if (tid == 0 && old != 511) {
      while (atomicAdd(flagA, 0u) == 0u) {}
    }
    __syncthreads();
    __threadfence();
    const int c0 = (old - 496) * 32;
    hs[tid] = hdst[tid];
    hs[tid + 256] = hdst[tid + 256];
    __syncthreads();
    const int col = c0 + (tid & 31), seg = tid >> 5;  // 8 segs x 64
    float acc = 0.f;
    for (int i = seg * 64; i < seg * 64 + 64; ++i)
      acc = fmaf(hs[i], hop_wq[(size_t)i * 512 + col], acc);
    red2[tid] = acc;
    __syncthreads();
    if (tid < 32) {
      float sm = 0.f;
#pragma unroll
      for (int g2 = 0; g2 < 8; ++g2) sm += red2[tid + 32 * g2];
      b1[c0 + tid] = sm;
    }
  }
}

// ================= B: hop sweep; last-8 blocks: qn slices -> micro-sync -> b2 slices =================
__launch_bounds__(1024)
__global__ void k_B(const ushort* __restrict__ feat, const float* __restrict__ b1,
                    const float* __restrict__ hop_v, const float* __restrict__ attn_wq,
                    float* __restrict__ qp, float* __restrict__ bZh, float* __restrict__ qn,
                    float* __restrict__ b2, unsigned* __restrict__ cntB,
                    unsigned* __restrict__ flagB, unsigned* __restrict__ cntB2,
                    unsigned* __restrict__ flagB2) {
  __shared__ float qbuf[16][512];
  __shared__ float sz[16];
  __shared__ float red[1024];
  __shared__ int sOld;
  const int tid = threadIdx.x, blk = blockIdx.x;
  const int w = tid >> 6, lane = tid & 63;
  float bv[8], vv[8], qa[8];
#pragma unroll
  for (int j = 0; j < 8; ++j) { bv[j] = b1[lane * 8 + j]; vv[j] = hop_v[lane * 8 + j]; qa[j] = 0.f; }
  float Z = 0.f;
  const int wv = blk * 16 + w;
  for (int m = wv; m < NROWS; m += 16 * HOPB) {
    const uint4 U = ((const uint4*)(feat + (size_t)m * HH))[lane];
    float f[8] = {bflo(U.x), bfhi(U.x), bflo(U.y), bfhi(U.y),
                  bflo(U.z), bfhi(U.z), bflo(U.w), bfhi(U.w)};
    float s = 0.f;
#pragma unroll
    for (int j = 0; j < 8; ++j) s += ftanh(f[j] + bv[j]) * vv[j];
#pragma unroll
    for (int off = 32; off > 0; off >>= 1) s += __shfl_xor(s, off);
    const float e = fexp(s);
    Z += e;
#pragma unroll
    for (int j = 0; j < 8; ++j) qa[j] = fmaf(e, f[j], qa[j]);
  }
  if (lane == 0) sz[w] = Z;
#pragma unroll
  for (int j = 0; j < 8; ++j) qbuf[w][lane * 8 + j] = qa[j];
  __syncthreads();
  {
    const int col = tid & 511, half = tid >> 9;
    float a = 0.f;
#pragma unroll
    for (int w2 = half * 8; w2 < half * 8 + 8; ++w2) a += qbuf[w2][col];
    red[tid] = a;
  }
  __syncthreads();
  if (tid < 512) qp[(size_t)blk * 512 + tid] = red[tid] + red[tid + 512];
  if (tid == 0) {
    float z = 0.f;
#pragma unroll
    for (int w2 = 0; w2 < 16; ++w2) z += sz[w2];
    bZh[blk] = z;
  }
  __syncthreads();
  if (tid == 0) {
    __threadfence();
    unsigned old = atomicAdd(cntB, 1u);
    if (old == HOPB - 1u) { atomicExch(flagB, 1u); *cntB = 0u; }
    sOld = (int)old;
  }
  __syncthreads();
  const int old = sOld;
  if (old >= HOPB - 8) {
    const int li = old - (HOPB - 8);
    if (tid == 0 && old != HOPB - 1) {
      while (atomicAdd(flagB, 0u) == 0u) {}
    }
    __syncthreads();
    __threadfence();
    // Zt (redundant reduce of 512 partial Z)
    red[tid] = (tid < HOPB) ? bZh[tid] : 0.f;
    __syncthreads();
    for (int s2 = 512; s2 > 0; s2 >>= 1) {
      if (tid < s2) red[tid] += red[tid + s2];
      __syncthreads();
    }
    const float Zt = red[0];
    __syncthreads();
    // qn slice [li*64, +64)
    {
      const int i = li * 64 + (tid & 63), ps = tid >> 6;  // 16 segs x 32 p
      float a = 0.f;
      for (int p = ps * 32; p < ps * 32 + 32; ++p) a += qp[(size_t)p * 512 + i];
      red[tid] = a;
      __syncthreads();
      if (tid < 64) {
        float sm = 0.f;
#pragma unroll
        for (int s2 = 0; s2 < 16; ++s2) sm += red[tid + 64 * s2];
        qn[li * 64 + tid] = sm / Zt;
      }
    }
    __threadfence();
    __syncthreads();
    if (tid == 0) {
      unsigned o2 = atomicAdd(cntB2, 1u);
      if (o2 == 7u) {
        atomicExch(flagB2, 1u);
        *cntB2 = 0u;
      } else {
        while (atomicAdd(flagB2, 0u) == 0u) {}
      }
    }
    __syncthreads();
    __threadfence();
    // b2 slice [li*64, +64)
    {
      const int j = li * 64 + (tid & 63), is = tid >> 6;  // 16 segs x 32 i
      float a = 0.f;
      for (int i2 = is * 32; i2 < is * 32 + 32; ++i2)
        a = fmaf(qn[i2], attn_wq[(size_t)i2 * 512 + j], a);
      red[tid] = a;
      __syncthreads();
      if (tid < 64) {
        float sm = 0.f;
#pragma unroll
        for (int s2 = 0; s2 < 16; ++s2) sm += red[tid + 64 * s2];
        b2[li * 64 + tid] = sm;
      }
    }
  }
}

// ================= C: attn transposed sweep (256 rows/block, uint2); last block: sample =================
__launch_bounds__(512)
__global__ void k_C(const ushort* __restrict__ featT, const float* __restrict__ b2,
                    const float* __restrict__ av, int* __restrict__ sel,
                    const float* __restrict__ gum, float* __restrict__ sc,
                    float* __restrict__ bZa, ull* __restrict__ bkey,
                    int* __restrict__ done_buf, int* __restrict__ xrow_buf,
                    float* __restrict__ outf, unsigned* __restrict__ cntC, int t) {
  __shared__ float spart[8][256];
  __shared__ float rz[512];
  __shared__ ull rk[512];
  __shared__ int isLast;
  const int tid = threadIdx.x, g = blockIdx.x;
  const int w = tid >> 6, lane = tid & 63;
  const int mb = g * 256 + lane * 4;
  const int h0 = w * 64;
  const ushort* fp = featT + (size_t)h0 * NP + mb;
  float a0 = 0.f, a1 = 0.f, a2 = 0.f, a3 = 0.f;
#pragma unroll 8
  for (int hh = 0; hh < 64; ++hh) {
    const uint2 u = *(const uint2*)fp;
    fp += NP;
    const float bb = b2[h0 + hh], vv = av[h0 + hh];
    a0 += ftanh(bflo(u.x) + bb) * vv;
    a1 += ftanh(bfhi(u.x) + bb) * vv;
    a2 += ftanh(bflo(u.y) + bb) * vv;
    a3 += ftanh(bfhi(u.y) + bb) * vv;
  }
  spart[w][lane * 4 + 0] = a0;
  spart[w][lane * 4 + 1] = a1;
  spart[w][lane * 4 + 2] = a2;
  spart[w][lane * 4 + 3] = a3;
  __syncthreads();
  if (w < 4) {
    const int idx = w * 64 + lane;  // 0..255
    const int m = g * 256 + idx;
    float s = 0.f;
#pragma unroll
    for (int w2 = 0; w2 < 8; ++w2) s += spart[w2][idx];
    const bool valid = (m < NROWS);
    float Z;
    ull key;
    if (valid) {
      float se = sel[m] ? NEGV : s;
      sc[m] = se;
      key = ((ull)fkey(se + gum[m]) << 32) | (unsigned)(NITEMS - m);
      Z = fexp(se);
    } else {
      key = 0;
      Z = 0.f;
    }
#pragma unroll
    for (int off = 32; off > 0; off >>= 1) {
      Z += __shfl_xor(Z, off);
      ull Ko = __shfl_xor(key, off);
      if (Ko > key) key = Ko;
    }
    if (lane == 0) { bZa[g * 4 + w] = Z; bkey[g * 4 + w] = key; }
  }
  __syncthreads();
  if (tid == 0) {
    __threadfence();
    unsigned old = atomicAdd(cntC, 1u);
    isLast = (old == gridDim.x - 1);
    if (isLast) *cntC = 0u;
  }
  __syncthreads();
  if (isLast) {
    __threadfence();
    float Zl = 0.f;
    ull Kl = 0;
    for (int i = tid; i < NGRP; i += 512) {
      Zl += bZa[i];
      ull k = bkey[i];
      if (k > Kl) Kl = k;
    }
    rz[tid] = Zl;
    rk[tid] = Kl;
    __syncthreads();
    for (int s2 = 256; s2 > 0; s2 >>= 1) {
      if (tid < s2) {
        rz[tid] += rz[tid + s2];
        if (rk[tid + s2] > rk[tid]) rk[tid] = rk[tid + s2];
      }
      __syncthreads();
    }
    if (tid == 0) {
      const float Z = rz[0];
      const ull K = rk[0];
      const int out = NITEMS - (int)(unsigned)(K & 0xffffffffull);
      const int d_in = (t == 0) ? 0 : *done_buf;
      const int xprev = (t == 0) ? -1 : *xrow_buf;
      const int nd = d_in | (out == NITEMS);
      outf[t] = (float)(d_in ? NITEMS : out);
      outf[TT + t] = d_in ? 0.f : (sc[out] - logf(Z));
      if (!d_in) sel[out] = 1;
      *done_buf = nd;
      *xrow_buf = nd ? xprev : out;
    }
  }
}

// ======================================================================
extern "C" void kernel_launch(void* const* d_in, const int* in_sizes, int n_in,
                              void* d_out, int out_size, void* d_ws, size_t ws_size,
                              hipStream_t stream) {
  const float* attn_mem = (const float*)d_in[0];
  const float* stoprow  = (const float*)d_in[1];
  const float* init_h   = (const float*)d_in[2];
  const float* init_c   = (const float*)d_in[3];
  const float* init_i   = (const float*)d_in[4];
  const float* attn_wm  = (const float*)d_in[5];
  const float* attn_wq  = (const float*)d_in[6];
  const float* attn_v   = (const float*)d_in[7];
  const float* hop_wm   = (const float*)d_in[8];
  const float* hop_wq   = (const float*)d_in[9];
  const float* hop_v    = (const float*)d_in[10];
  const float* w_ih     = (const float*)d_in[11];
  const float* w_hh     = (const float*)d_in[12];
  const float* b_ih     = (const float*)d_in[13];
  const float* b_hh     = (const float*)d_in[14];
  const float* gumbel   = (const float*)d_in[15];

  float* ws = (float*)d_ws;
  size_t fo = 0;
  const size_t FB = (size_t)NP * 512 / 2;
  ushort* hop_feat   = (ushort*)(ws + fo); fo += FB;
  ushort* attn_featT = (ushort*)(ws + fo); fo += FB;
  ushort* Ahi = (ushort*)(ws + fo); fo += FB;
  ushort* Alo = (ushort*)(ws + fo); fo += FB;
  ushort* WhiT_a = (ushort*)(ws + fo); fo += 131072;
  ushort* WloT_a = (ushort*)(ws + fo); fo += 131072;
  ushort* WhiT_h = (ushort*)(ws + fo); fo += 131072;
  ushort* WloT_h = (ushort*)(ws + fo); fo += 131072;
  float* sc  = ws + fo; fo += NP;
  int* sel   = (int*)(ws + fo); fo += NP;
  float* qp  = ws + fo; fo += (size_t)HOPB * 512;
  float* bZh = ws + fo; fo += HOPB;
  float* bZa = ws + fo; fo += 1024;
  ull* bkey  = (ull*)(ws + fo); fo += 2048;
  float* hv0 = ws + fo; fo += HH;
  float* hv1 = ws + fo; fo += HH;
  float* cv0 = ws + fo; fo += HH;
  float* cv1 = ws + fo; fo += HH;
  float* b1  = ws + fo; fo += HH;
  float* b2  = ws + fo; fo += HH;
  float* qn  = ws + fo; fo += HH;
  unsigned* cnts = (unsigned*)(ws + fo); fo += 80;
  int* done_buf = (int*)(ws + fo); fo += 2;
  int* xrow_buf = (int*)(ws + fo); fo += 2;
  if (fo * sizeof(float) > ws_size) return;

  float* outf = (float*)d_out;

  k_zero<<<NP / 256, 256, 0, stream>>>(sel, cnts);
  k_convA<<<(NP * 512 / 8) / 256, 256, 0, stream>>>(attn_mem, stoprow, Ahi, Alo);
  k_convBT<<<512, 256, 0, stream>>>(attn_wm, WhiT_a, WloT_a);
  k_convBT<<<512, 256, 0, stream>>>(hop_wm, WhiT_h, WloT_h);

  dim3 ggrid(4, NP / 128);  // 1568 blocks = 8*196
  k_mfma<1><<<ggrid, 256, 0, stream>>>(Ahi, Alo, WhiT_a, WloT_a, attn_featT);
  k_mfma<0><<<ggrid, 256, 0, stream>>>(Ahi, Alo, WhiT_h, WloT_h, hop_feat);

  for (int t = 0; t < TT; ++t) {
    k_A<<<512, 256, 0, stream>>>(attn_mem, stoprow, init_i, init_h, init_c,
                                 w_ih, w_hh, b_ih, b_hh, hop_wq,
                                 hv0, hv1, cv0, cv1, b1, xrow_buf,
                                 cnts + 0, cnts + 16 + t, t);
    k_B<<<HOPB, 1024, 0, stream>>>(hop_feat, b1, hop_v, attn_wq, qp, bZh, qn, b2,
                                   cnts + 1, cnts + 32 + t, cnts + 3, cnts + 48 + t);
    k_C<<<NGC, 512, 0, stream>>>(attn_featT, b2, attn_v, sel,
                                 gumbel + (size_t)t * NROWS, sc, bZa, bkey,
                                 done_buf, xrow_buf, outf, cnts + 2, t);
  }
}

// Round 14
// 1767.638 us; speedup vs baseline: 2.8577x; 1.0933x over previous
//
#include <hip/hip_runtime.h>
#include <math.h>

#define NITEMS 50000
#define NROWS 50001
#define NP 50176          // padded row count (392*128 = 196*256)
#define DD 512
#define HH 512
#define TT 16
#define NEGV (-1e18f)
#define NGRP 784          // 196 blocks x 4 partials
#define NGC 196           // k_C blocks (256 rows each)
#define HOPB 512          // k_B grid (x16 waves = 8192 waves)

typedef unsigned long long ull;
typedef unsigned short ushort;
typedef short short8 __attribute__((ext_vector_type(8)));
typedef float f32x4 __attribute__((ext_vector_type(4)));

__device__ __forceinline__ unsigned fkey(float f) {
  unsigned u = __float_as_uint(f);
  return (u & 0x80000000u) ? ~u : (u | 0x80000000u);
}
__device__ __forceinline__ float ftanh(float x) {
  float e = __builtin_amdgcn_exp2f(x * 2.885390081777927f);
  return 1.f - 2.f * __builtin_amdgcn_rcpf(e + 1.f);
}
__device__ __forceinline__ float fexp(float x) {
  return __builtin_amdgcn_exp2f(x * 1.4426950408889634f);
}
__device__ __forceinline__ ushort rne1(float a) {
  unsigned u = __float_as_uint(a);
  return (ushort)((u + 0x7fffu + ((u >> 16) & 1u)) >> 16);
}
__device__ __forceinline__ float bf2f(ushort h) { return __uint_as_float((unsigned)h << 16); }
__device__ __forceinline__ unsigned pack_bf16(float a, float b) {
  return (unsigned)rne1(a) | ((unsigned)rne1(b) << 16);
}
__device__ __forceinline__ float bflo(unsigned u) { return __uint_as_float(u << 16); }
__device__ __forceinline__ float bfhi(unsigned u) { return __uint_as_float(u & 0xffff0000u); }

__device__ __forceinline__ void gl_lds16(const void* g, void* l) {
#if __has_builtin(__builtin_amdgcn_global_load_lds)
  __builtin_amdgcn_global_load_lds((const __attribute__((address_space(1))) unsigned*)g,
                                   (__attribute__((address_space(3))) unsigned*)l, 16, 0, 0);
#else
  const int lane = threadIdx.x & 63;
  *(uint4*)((char*)l + lane * 16) = *(const uint4*)g;
#endif
}

#define MFMA(a, b, c) __builtin_amdgcn_mfma_f32_16x16x32_bf16(a, b, c, 0, 0, 0)

// ---------------- A -> (Ahi, Alo) bf16 [NP][512] ----------------
__global__ void k_convA(const float* __restrict__ A0, const float* __restrict__ stoprow,
                        ushort* __restrict__ Ahi, ushort* __restrict__ Alo) {
  const size_t t = (size_t)blockIdx.x * 256 + threadIdx.x;
  const size_t base = t * 8;
  const int row = (int)(base >> 9);
  float v[8];
  if (row < NITEMS) {
    const float4* p = (const float4*)(A0 + base);
    float4 x = p[0], y = p[1];
    v[0] = x.x; v[1] = x.y; v[2] = x.z; v[3] = x.w;
    v[4] = y.x; v[5] = y.y; v[6] = y.z; v[7] = y.w;
  } else if (row == NITEMS) {
    const float4* p = (const float4*)(stoprow + (base & 511));
    float4 x = p[0], y = p[1];
    v[0] = x.x; v[1] = x.y; v[2] = x.z; v[3] = x.w;
    v[4] = y.x; v[5] = y.y; v[6] = y.z; v[7] = y.w;
  } else {
#pragma unroll
    for (int j = 0; j < 8; ++j) v[j] = 0.f;
  }
  unsigned hw[4], lw[4];
#pragma unroll
  for (int j = 0; j < 4; ++j) {
    float a0 = v[2 * j], a1 = v[2 * j + 1];
    ushort h0 = rne1(a0), h1 = rne1(a1);
    hw[j] = (unsigned)h0 | ((unsigned)h1 << 16);
    lw[j] = pack_bf16(a0 - bf2f(h0), a1 - bf2f(h1));
  }
  *(uint4*)(Ahi + base) = make_uint4(hw[0], hw[1], hw[2], hw[3]);
  *(uint4*)(Alo + base) = make_uint4(lw[0], lw[1], lw[2], lw[3]);
}

// ---------------- W [k][n] -> transposed bf16 ----------------
__global__ void k_convBT(const float* __restrict__ W, ushort* __restrict__ WhiT,
                         ushort* __restrict__ WloT) {
  const int n = blockIdx.x;
  const int k0 = threadIdx.x * 2;
  float a0 = W[(size_t)k0 * 512 + n];
  float a1 = W[(size_t)(k0 + 1) * 512 + n];
  ushort h0 = rne1(a0), h1 = rne1(a1);
  *(unsigned*)(WhiT + (size_t)n * 512 + k0) = (unsigned)h0 | ((unsigned)h1 << 16);
  *(unsigned*)(WloT + (size_t)n * 512 + k0) = pack_bf16(a0 - bf2f(h0), a1 - bf2f(h1));
}

// ---------------- MFMA GEMM (verified R10; swizzle exact: 1568 = 8*196) ----------------
template <int TR>
__launch_bounds__(256, 2)
__global__ void k_mfma(const ushort* __restrict__ Ahi, const ushort* __restrict__ Alo,
                       const ushort* __restrict__ BhT, const ushort* __restrict__ BlT,
                       ushort* __restrict__ C) {
  __shared__ __align__(16) char lds[65536];
  char* sA0 = lds;
  char* sA1 = lds + 16384;
  char* sB0 = lds + 32768;
  char* sB1 = lds + 49152;
  const int tid = threadIdx.x;
  const int lane = tid & 63, w = tid >> 6;
  const int lid = blockIdx.y * 4 + blockIdx.x;
  const int xcd = lid & 7, pos = lid >> 3;
  const int orig = xcd * 196 + pos;
  const int m0 = (orig >> 2) * 128, n0 = (orig & 3) * 128;
  const int aR0 = (w & 1) * 64, bR0 = (w >> 1) * 64;

  f32x4 acc[4][4];
  const f32x4 z4 = {0.f, 0.f, 0.f, 0.f};
#pragma unroll
  for (int i = 0; i < 4; ++i)
#pragma unroll
    for (int j = 0; j < 4; ++j) acc[i][j] = z4;

#define STAGE_ALL(KT)                                                                     \
  {                                                                                       \
    _Pragma("unroll") for (int i = 0; i < 4; ++i) {                                       \
      const int row = i * 32 + (tid >> 3);                                                \
      const int kb = ((tid & 7) << 4) ^ ((row & 7) << 4);                                 \
      const int ldso = i * 4096 + (w << 10);                                              \
      gl_lds16((const char*)(Ahi + ((size_t)(m0 + row) << 9) + (KT)) + kb, sA0 + ldso);   \
      gl_lds16((const char*)(Alo + ((size_t)(m0 + row) << 9) + (KT)) + kb, sA1 + ldso);   \
      gl_lds16((const char*)(BhT + ((size_t)(n0 + row) << 9) + (KT)) + kb, sB0 + ldso);   \
      gl_lds16((const char*)(BlT + ((size_t)(n0 + row) << 9) + (KT)) + kb, sB1 + ldso);   \
    }                                                                                     \
  }

  STAGE_ALL(0)
  __syncthreads();
  for (int c = 0; c < 8; ++c) {
#pragma unroll
    for (int ks = 0; ks < 2; ++ks) {
      short8 ah[4], al[4], bh[4], bl[4];
      const int kbb = ks * 64 + ((lane >> 4) << 4);
#pragma unroll
      for (int f = 0; f < 4; ++f) {
        const int ra = aR0 + f * 16 + (lane & 15);
        const int oa = ra * 128 + (kbb ^ ((ra & 7) << 4));
        ah[f] = *(const short8*)(sA0 + oa);
        al[f] = *(const short8*)(sA1 + oa);
        const int rb = bR0 + f * 16 + (lane & 15);
        const int ob = rb * 128 + (kbb ^ ((rb & 7) << 4));
        bh[f] = *(const short8*)(sB0 + ob);
        bl[f] = *(const short8*)(sB1 + ob);
      }
#pragma unroll
      for (int mf = 0; mf < 4; ++mf)
#pragma unroll
        for (int nf = 0; nf < 4; ++nf) {
          acc[mf][nf] = MFMA(ah[mf], bh[nf], acc[mf][nf]);
          acc[mf][nf] = MFMA(ah[mf], bl[nf], acc[mf][nf]);
          acc[mf][nf] = MFMA(al[mf], bh[nf], acc[mf][nf]);
        }
    }
    if (c < 7) {
      __syncthreads();
      STAGE_ALL((c + 1) * 64)
      __syncthreads();
    }
  }
#undef STAGE_ALL

#pragma unroll
  for (int mf = 0; mf < 4; ++mf)
#pragma unroll
    for (int nf = 0; nf < 4; ++nf) {
      const f32x4 a = acc[mf][nf];
      const int n = n0 + bR0 + nf * 16 + (lane & 15);
      const int mb = m0 + aR0 + mf * 16 + ((lane >> 4) << 2);
      if (TR) {
        ushort* p = C + (size_t)n * NP + mb;
        *(uint2*)p = make_uint2(pack_bf16(a.x, a.y), pack_bf16(a.z, a.w));
      } else {
        C[(size_t)(mb + 0) * 512 + n] = rne1(a.x);
        C[(size_t)(mb + 1) * 512 + n] = rne1(a.y);
        C[(size_t)(mb + 2) * 512 + n] = rne1(a.z);
        C[(size_t)(mb + 3) * 512 + n] = rne1(a.w);
      }
    }
}

// ---------------- zero sel + counters/flags ----------------
__global__ void k_zero(int* __restrict__ sel, unsigned* __restrict__ cnts) {
  int i = blockIdx.x * 256 + threadIdx.x;
  if (i < NROWS) sel[i] = 0;
  if (blockIdx.x == 0 && threadIdx.x < 80) cnts[threadIdx.x] = 0;
}

// ================= A: LSTM gates + h,c; last-16 blocks: b1 slices =================
__launch_bounds__(256)
__global__ void k_A(const float* __restrict__ attn_mem, const float* __restrict__ stoprow,
                    const float* __restrict__ init_i, const float* __restrict__ init_h,
                    const float* __restrict__ init_c,
                    const float* __restrict__ w_ih, const float* __restrict__ w_hh,
                    const float* __restrict__ b_ih, const float* __restrict__ b_hh,
                    const float* __restrict__ hop_wq,
                    float* __restrict__ hv0, float* __restrict__ hv1,
                    float* __restrict__ cv0, float* __restrict__ cv1,
                    float* __restrict__ b1, const int* __restrict__ xrow_buf,
                    unsigned* __restrict__ cntA, unsigned* __restrict__ flagA, int t) {
  __shared__ float g4[4];
  __shared__ float hs[512];
  __shared__ float red2[256];
  __shared__ int sOld;
  const int b = blockIdx.x, tid = threadIdx.x, w = tid >> 6, lane = tid & 63;
  const int xrow = (t == 0) ? -1 : *xrow_buf;
  const float* xp = (xrow < 0) ? init_i
                               : ((xrow == NITEMS) ? stoprow : attn_mem + (size_t)xrow * DD);
  const float* hsrc = (t == 0) ? init_h : ((t & 1) ? hv0 : hv1);
  float* hdst = (t & 1) ? hv1 : hv0;
  const float* csrc = (t == 0) ? init_c : ((t & 1) ? cv0 : cv1);
  float* cdst = (t & 1) ? cv1 : cv0;

  const int r = w * 512 + b;  // gate section w, unit b
  const float4* x4 = (const float4*)xp;
  const float4* h4 = (const float4*)hsrc;
  const float4* wi = (const float4*)(w_ih + (size_t)r * DD);
  const float4* wh = (const float4*)(w_hh + (size_t)r * DD);
  float s = 0.f;
  float4 a, ww;
  a = x4[lane * 2];     ww = wi[lane * 2];     s += a.x * ww.x + a.y * ww.y + a.z * ww.z + a.w * ww.w;
  a = x4[lane * 2 + 1]; ww = wi[lane * 2 + 1]; s += a.x * ww.x + a.y * ww.y + a.z * ww.z + a.w * ww.w;
  a = h4[lane * 2];     ww = wh[lane * 2];     s += a.x * ww.x + a.y * ww.y + a.z * ww.z + a.w * ww.w;
  a = h4[lane * 2 + 1]; ww = wh[lane * 2 + 1]; s += a.x * ww.x + a.y * ww.y + a.z * ww.z + a.w * ww.w;
#pragma unroll
  for (int off = 32; off > 0; off >>= 1) s += __shfl_xor(s, off);
  if (lane == 0) g4[w] = s + b_ih[r] + b_hh[r];
  __syncthreads();
  if (tid == 0) {
    const float si = 1.f / (1.f + expf(-g4[0]));
    const float sf = 1.f / (1.f + expf(-g4[1]));
    const float so = 1.f / (1.f + expf(-g4[3]));
    const float cn = sf * csrc[b] + si * tanhf(g4[2]);
    cdst[b] = cn;
    hdst[b] = so * tanhf(cn);
  }
  __syncthreads();
  if (tid == 0) {
    __threadfence();
    unsigned old = atomicAdd(cntA, 1u);
    if (old == 511u) { atomicExch(flagA, 1u); *cntA = 0u; }
    sOld = (int)old;
  }
  __syncthreads();
  const int old = sOld;
  if (old >= 496) {
    if (tid == 0 && old != 511) {
      while (atomicAdd(flagA, 0u) == 0u) {}
    }
    __syncthreads();
    __threadfence();
    const int c0 = (old - 496) * 32;
    hs[tid] = hdst[tid];
    hs[tid + 256] = hdst[tid + 256];
    __syncthreads();
    const int col = c0 + (tid & 31), seg = tid >> 5;  // 8 segs x 64
    float acc = 0.f;
#pragma unroll 8
    for (int i = seg * 64; i < seg * 64 + 64; ++i)
      acc = fmaf(hs[i], hop_wq[(size_t)i * 512 + col], acc);
    red2[tid] = acc;
    __syncthreads();
    if (tid < 32) {
      float sm = 0.f;
#pragma unroll
      for (int g2 = 0; g2 < 8; ++g2) sm += red2[tid + 32 * g2];
      b1[c0 + tid] = sm;
    }
  }
}

// ================= B: hop sweep (prefetch d2); last-8 blocks: qn -> sync -> b2 (MLP tails) =================
__launch_bounds__(1024)
__global__ void k_B(const ushort* __restrict__ feat, const float* __restrict__ b1,
                    const float* __restrict__ hop_v, const float* __restrict__ attn_wq,
                    float* __restrict__ qp, float* __restrict__ bZh, float* __restrict__ qn,
                    float* __restrict__ b2, unsigned* __restrict__ cntB,
                    unsigned* __restrict__ flagB, unsigned* __restrict__ cntB2,
                    unsigned* __restrict__ flagB2) {
  __shared__ float qbuf[16][512];
  __shared__ float sz[16];
  __shared__ float red[1024];
  __shared__ int sOld;
  const int tid = threadIdx.x, blk = blockIdx.x;
  const int w = tid >> 6, lane = tid & 63;
  float bv[8], vv[8], qa[8];
#pragma unroll
  for (int j = 0; j < 8; ++j) { bv[j] = b1[lane * 8 + j]; vv[j] = hop_v[lane * 8 + j]; qa[j] = 0.f; }
  float Z = 0.f;
  const int wv = blk * 16 + w;
  {
    int m = wv;
    uint4 U = ((const uint4*)(feat + (size_t)m * HH))[lane];
    while (m < NROWS) {
      const int mn = m + 16 * HOPB;
      const uint4 Un = ((const uint4*)(feat + (size_t)(mn < NROWS ? mn : 0) * HH))[lane];
      float f[8] = {bflo(U.x), bfhi(U.x), bflo(U.y), bfhi(U.y),
                    bflo(U.z), bfhi(U.z), bflo(U.w), bfhi(U.w)};
      float s = 0.f;
#pragma unroll
      for (int j = 0; j < 8; ++j) s += ftanh(f[j] + bv[j]) * vv[j];
#pragma unroll
      for (int off = 32; off > 0; off >>= 1) s += __shfl_xor(s, off);
      const float e = fexp(s);
      Z += e;
#pragma unroll
      for (int j = 0; j < 8; ++j) qa[j] = fmaf(e, f[j], qa[j]);
      U = Un;
      m = mn;
    }
  }
  if (lane == 0) sz[w] = Z;
#pragma unroll
  for (int j = 0; j < 8; ++j) qbuf[w][lane * 8 + j] = qa[j];
  __syncthreads();
  {
    const int col = tid & 511, half = tid >> 9;
    float a = 0.f;
#pragma unroll
    for (int w2 = half * 8; w2 < half * 8 + 8; ++w2) a += qbuf[w2][col];
    red[tid] = a;
  }
  __syncthreads();
  if (tid < 512) qp[(size_t)blk * 512 + tid] = red[tid] + red[tid + 512];
  if (tid == 0) {
    float z = 0.f;
#pragma unroll
    for (int w2 = 0; w2 < 16; ++w2) z += sz[w2];
    bZh[blk] = z;
  }
  __syncthreads();
  if (tid == 0) {
    __threadfence();
    unsigned old = atomicAdd(cntB, 1u);
    if (old == HOPB - 1u) { atomicExch(flagB, 1u); *cntB = 0u; }
    sOld = (int)old;
  }
  __syncthreads();
  const int old = sOld;
  if (old >= HOPB - 8) {
    const int li = old - (HOPB - 8);
    if (tid == 0 && old != HOPB - 1) {
      while (atomicAdd(flagB, 0u) == 0u) {}
    }
    __syncthreads();
    __threadfence();
    // Zt (redundant reduce of 512 partial Z)
    red[tid] = (tid < HOPB) ? bZh[tid] : 0.f;
    __syncthreads();
    for (int s2 = 512; s2 > 0; s2 >>= 1) {
      if (tid < s2) red[tid] += red[tid + s2];
      __syncthreads();
    }
    const float Zt = red[0];
    __syncthreads();
    // qn slice [li*64, +64)  (unroll -> MLP)
    {
      const int i = li * 64 + (tid & 63), ps = tid >> 6;  // 16 segs x 32 p
      float a = 0.f;
#pragma unroll 8
      for (int p = ps * 32; p < ps * 32 + 32; ++p) a += qp[(size_t)p * 512 + i];
      red[tid] = a;
      __syncthreads();
      if (tid < 64) {
        float sm = 0.f;
#pragma unroll
        for (int s2 = 0; s2 < 16; ++s2) sm += red[tid + 64 * s2];
        qn[li * 64 + tid] = sm / Zt;
      }
    }
    __threadfence();
    __syncthreads();
    if (tid == 0) {
      unsigned o2 = atomicAdd(cntB2, 1u);
      if (o2 == 7u) {
        atomicExch(flagB2, 1u);
        *cntB2 = 0u;
      } else {
        while (atomicAdd(flagB2, 0u) == 0u) {}
      }
    }
    __syncthreads();
    __threadfence();
    // b2 slice [li*64, +64)  (unroll -> MLP)
    {
      const int j = li * 64 + (tid & 63), is = tid >> 6;  // 16 segs x 32 i
      float a = 0.f;
#pragma unroll 8
      for (int i2 = is * 32; i2 < is * 32 + 32; ++i2)
        a = fmaf(qn[i2], attn_wq[(size_t)i2 * 512 + j], a);
      red[tid] = a;
      __syncthreads();
      if (tid < 64) {
        float sm = 0.f;
#pragma unroll
        for (int s2 = 0; s2 < 16; ++s2) sm += red[tid + 64 * s2];
        b2[li * 64 + tid] = sm;
      }
    }
  }
}

// ================= C: attn transposed sweep (256 rows/block, uint2); last block: sample =================
__launch_bounds__(512)
__global__ void k_C(const ushort* __restrict__ featT, const float* __restrict__ b2,
                    const float* __restrict__ av, int* __restrict__ sel,
                    const float* __restrict__ gum, float* __restrict__ sc,
                    float* __restrict__ bZa, ull* __restrict__ bkey,
                    int* __restrict__ done_buf, int* __restrict__ xrow_buf,
                    float* __restrict__ outf, unsigned* __restrict__ cntC, int t) {
  __shared__ float spart[8][256];
  __shared__ float rz[512];
  __shared__ ull rk[512];
  __shared__ int isLast;
  const int tid = threadIdx.x, g = blockIdx.x;
  const int w = tid >> 6, lane = tid & 63;
  const int mb = g * 256 + lane * 4;
  const int h0 = w * 64;
  const ushort* fp = featT + (size_t)h0 * NP + mb;
  float a0 = 0.f, a1 = 0.f, a2 = 0.f, a3 = 0.f;
#pragma unroll 8
  for (int hh = 0; hh < 64; ++hh) {
    const uint2 u = *(const uint2*)fp;
    fp += NP;
    const float bb = b2[h0 + hh], vv = av[h0 + hh];
    a0 += ftanh(bflo(u.x) + bb) * vv;
    a1 += ftanh(bfhi(u.x) + bb) * vv;
    a2 += ftanh(bflo(u.y) + bb) * vv;
    a3 += ftanh(bfhi(u.y) + bb) * vv;
  }
  spart[w][lane * 4 + 0] = a0;
  spart[w][lane * 4 + 1] = a1;
  spart[w][lane * 4 + 2] = a2;
  spart[w][lane * 4 + 3] = a3;
  __syncthreads();
  if (w < 4) {
    const int idx = w * 64 + lane;  // 0..255
    const int m = g * 256 + idx;
    float s = 0.f;
#pragma unroll
    for (int w2 = 0; w2 < 8; ++w2) s += spart[w2][idx];
    const bool valid = (m < NROWS);
    float Z;
    ull key;
    if (valid) {
      float se = sel[m] ? NEGV : s;
      sc[m] = se;
      key = ((ull)fkey(se + gum[m]) << 32) | (unsigned)(NITEMS - m);
      Z = fexp(se);
    } else {
      key = 0;
      Z = 0.f;
    }
#pragma unroll
    for (int off = 32; off > 0; off >>= 1) {
      Z += __shfl_xor(Z, off);
      ull Ko = __shfl_xor(key, off);
      if (Ko > key) key = Ko;
    }
    if (lane == 0) { bZa[g * 4 + w] = Z; bkey[g * 4 + w] = key; }
  }
  __syncthreads();
  if (tid == 0) {
    __threadfence();
    unsigned old = atomicAdd(cntC, 1u);
    isLast = (old == gridDim.x - 1);
    if (isLast) *cntC = 0u;
  }
  __syncthreads();
  if (isLast) {
    __threadfence();
    float Zl = 0.f;
    ull Kl = 0;
    for (int i = tid; i < NGRP; i += 512) {
      Zl += bZa[i];
      ull k = bkey[i];
      if (k > Kl) Kl = k;
    }
    rz[tid] = Zl;
    rk[tid] = Kl;
    __syncthreads();
    for (int s2 = 256; s2 > 0; s2 >>= 1) {
      if (tid < s2) {
        rz[tid] += rz[tid + s2];
        if (rk[tid + s2] > rk[tid]) rk[tid] = rk[tid + s2];
      }
      __syncthreads();
    }
    if (tid == 0) {
      const float Z = rz[0];
      const ull K = rk[0];
      const int out = NITEMS - (int)(unsigned)(K & 0xffffffffull);
      const int d_in = (t == 0) ? 0 : *done_buf;
      const int xprev = (t == 0) ? -1 : *xrow_buf;
      const int nd = d_in | (out == NITEMS);
      outf[t] = (float)(d_in ? NITEMS : out);
      outf[TT + t] = d_in ? 0.f : (sc[out] - logf(Z));
      if (!d_in) sel[out] = 1;
      *done_buf = nd;
      *xrow_buf = nd ? xprev : out;
    }
  }
}

// ======================================================================
extern "C" void kernel_launch(void* const* d_in, const int* in_sizes, int n_in,
                              void* d_out, int out_size, void* d_ws, size_t ws_size,
                              hipStream_t stream) {
  const float* attn_mem = (const float*)d_in[0];
  const float* stoprow  = (const float*)d_in[1];
  const float* init_h   = (const float*)d_in[2];
  const float* init_c   = (const float*)d_in[3];
  const float* init_i   = (const float*)d_in[4];
  const float* attn_wm  = (const float*)d_in[5];
  const float* attn_wq  = (const float*)d_in[6];
  const float* attn_v   = (const float*)d_in[7];
  const float* hop_wm   = (const float*)d_in[8];
  const float* hop_wq   = (const float*)d_in[9];
  const float* hop_v    = (const float*)d_in[10];
  const float* w_ih     = (const float*)d_in[11];
  const float* w_hh     = (const float*)d_in[12];
  const float* b_ih     = (const float*)d_in[13];
  const float* b_hh     = (const float*)d_in[14];
  const float* gumbel   = (const float*)d_in[15];

  float* ws = (float*)d_ws;
  size_t fo = 0;
  const size_t FB = (size_t)NP * 512 / 2;
  ushort* hop_feat   = (ushort*)(ws + fo); fo += FB;
  ushort* attn_featT = (ushort*)(ws + fo); fo += FB;
  ushort* Ahi = (ushort*)(ws + fo); fo += FB;
  ushort* Alo = (ushort*)(ws + fo); fo += FB;
  ushort* WhiT_a = (ushort*)(ws + fo); fo += 131072;
  ushort* WloT_a = (ushort*)(ws + fo); fo += 131072;
  ushort* WhiT_h = (ushort*)(ws + fo); fo += 131072;
  ushort* WloT_h = (ushort*)(ws + fo); fo += 131072;
  float* sc  = ws + fo; fo += NP;
  int* sel   = (int*)(ws + fo); fo += NP;
  float* qp  = ws + fo; fo += (size_t)HOPB * 512;
  float* bZh = ws + fo; fo += HOPB;
  float* bZa = ws + fo; fo += 1024;
  ull* bkey  = (ull*)(ws + fo); fo += 2048;
  float* hv0 = ws + fo; fo += HH;
  float* hv1 = ws + fo; fo += HH;
  float* cv0 = ws + fo; fo += HH;
  float* cv1 = ws + fo; fo += HH;
  float* b1  = ws + fo; fo += HH;
  float* b2  = ws + fo; fo += HH;
  float* qn  = ws + fo; fo += HH;
  unsigned* cnts = (unsigned*)(ws + fo); fo += 80;
  int* done_buf = (int*)(ws + fo); fo += 2;
  int* xrow_buf = (int*)(ws + fo); fo += 2;
  if (fo * sizeof(float) > ws_size) return;

  float* outf = (float*)d_out;

  k_zero<<<NP / 256, 256, 0, stream>>>(sel, cnts);
  k_convA<<<(NP * 512 / 8) / 256, 256, 0, stream>>>(attn_mem, stoprow, Ahi, Alo);
  k_convBT<<<512, 256, 0, stream>>>(attn_wm, WhiT_a, WloT_a);
  k_convBT<<<512, 256, 0, stream>>>(hop_wm, WhiT_h, WloT_h);

  dim3 ggrid(4, NP / 128);  // 1568 blocks = 8*196
  k_mfma<1><<<ggrid, 256, 0, stream>>>(Ahi, Alo, WhiT_a, WloT_a, attn_featT);
  k_mfma<0><<<ggrid, 256, 0, stream>>>(Ahi, Alo, WhiT_h, WloT_h, hop_feat);

  for (int t = 0; t < TT; ++t) {
    k_A<<<512, 256, 0, stream>>>(attn_mem, stoprow, init_i, init_h, init_c,
                                 w_ih, w_hh, b_ih, b_hh, hop_wq,
                                 hv0, hv1, cv0, cv1, b1, xrow_buf,
                                 cnts + 0, cnts + 16 + t, t);
    k_B<<<HOPB, 1024, 0, stream>>>(hop_feat, b1, hop_v, attn_wq, qp, bZh, qn, b2,
                                   cnts + 1, cnts + 32 + t, cnts + 3, cnts + 48 + t);
    k_C<<<NGC, 512, 0, stream>>>(attn_featT, b2, attn_v, sel,
                                 gumbel + (size_t)t * NROWS, sc, bZa, bkey,
                                 done_buf, xrow_buf, outf, cnts + 2, t);
  }
}

// Round 15
// 1636.017 us; speedup vs baseline: 3.0876x; 1.0805x over previous
//
#include <hip/hip_runtime.h>
#include <math.h>

#define NITEMS 50000
#define NROWS 50001
#define NP 50176          // padded row count (392*128 = 196*256)
#define DD 512
#define HH 512
#define TT 16
#define NEGV (-1e18f)
#define NGRP 784          // 196 blocks x 4 partials
#define NGC 196           // transposed-sweep blocks (256 rows each)

typedef unsigned long long ull;
typedef unsigned short ushort;
typedef short short8 __attribute__((ext_vector_type(8)));
typedef float f32x4 __attribute__((ext_vector_type(4)));

__device__ __forceinline__ unsigned fkey(float f) {
  unsigned u = __float_as_uint(f);
  return (u & 0x80000000u) ? ~u : (u | 0x80000000u);
}
__device__ __forceinline__ float ftanh(float x) {
  float e = __builtin_amdgcn_exp2f(x * 2.885390081777927f);
  return 1.f - 2.f * __builtin_amdgcn_rcpf(e + 1.f);
}
__device__ __forceinline__ float fexp(float x) {
  return __builtin_amdgcn_exp2f(x * 1.4426950408889634f);
}
__device__ __forceinline__ ushort rne1(float a) {
  unsigned u = __float_as_uint(a);
  return (ushort)((u + 0x7fffu + ((u >> 16) & 1u)) >> 16);
}
__device__ __forceinline__ float bf2f(ushort h) { return __uint_as_float((unsigned)h << 16); }
__device__ __forceinline__ unsigned pack_bf16(float a, float b) {
  return (unsigned)rne1(a) | ((unsigned)rne1(b) << 16);
}
__device__ __forceinline__ float bflo(unsigned u) { return __uint_as_float(u << 16); }
__device__ __forceinline__ float bfhi(unsigned u) { return __uint_as_float(u & 0xffff0000u); }

__device__ __forceinline__ void gl_lds16(const void* g, void* l) {
#if __has_builtin(__builtin_amdgcn_global_load_lds)
  __builtin_amdgcn_global_load_lds((const __attribute__((address_space(1))) unsigned*)g,
                                   (__attribute__((address_space(3))) unsigned*)l, 16, 0, 0);
#else
  const int lane = threadIdx.x & 63;
  *(uint4*)((char*)l + lane * 16) = *(const uint4*)g;
#endif
}

#define MFMA(a, b, c) __builtin_amdgcn_mfma_f32_16x16x32_bf16(a, b, c, 0, 0, 0)

// ---------------- A -> (Ahi, Alo) bf16 [NP][512] ----------------
__global__ void k_convA(const float* __restrict__ A0, const float* __restrict__ stoprow,
                        ushort* __restrict__ Ahi, ushort* __restrict__ Alo) {
  const size_t t = (size_t)blockIdx.x * 256 + threadIdx.x;
  const size_t base = t * 8;
  const int row = (int)(base >> 9);
  float v[8];
  if (row < NITEMS) {
    const float4* p = (const float4*)(A0 + base);
    float4 x = p[0], y = p[1];
    v[0] = x.x; v[1] = x.y; v[2] = x.z; v[3] = x.w;
    v[4] = y.x; v[5] = y.y; v[6] = y.z; v[7] = y.w;
  } else if (row == NITEMS) {
    const float4* p = (const float4*)(stoprow + (base & 511));
    float4 x = p[0], y = p[1];
    v[0] = x.x; v[1] = x.y; v[2] = x.z; v[3] = x.w;
    v[4] = y.x; v[5] = y.y; v[6] = y.z; v[7] = y.w;
  } else {
#pragma unroll
    for (int j = 0; j < 8; ++j) v[j] = 0.f;
  }
  unsigned hw[4], lw[4];
#pragma unroll
  for (int j = 0; j < 4; ++j) {
    float a0 = v[2 * j], a1 = v[2 * j + 1];
    ushort h0 = rne1(a0), h1 = rne1(a1);
    hw[j] = (unsigned)h0 | ((unsigned)h1 << 16);
    lw[j] = pack_bf16(a0 - bf2f(h0), a1 - bf2f(h1));
  }
  *(uint4*)(Ahi + base) = make_uint4(hw[0], hw[1], hw[2], hw[3]);
  *(uint4*)(Alo + base) = make_uint4(lw[0], lw[1], lw[2], lw[3]);
}

// ---------------- W [k][n] -> transposed bf16 ----------------
__global__ void k_convBT(const float* __restrict__ W, ushort* __restrict__ WhiT,
                         ushort* __restrict__ WloT) {
  const int n = blockIdx.x;
  const int k0 = threadIdx.x * 2;
  float a0 = W[(size_t)k0 * 512 + n];
  float a1 = W[(size_t)(k0 + 1) * 512 + n];
  ushort h0 = rne1(a0), h1 = rne1(a1);
  *(unsigned*)(WhiT + (size_t)n * 512 + k0) = (unsigned)h0 | ((unsigned)h1 << 16);
  *(unsigned*)(WloT + (size_t)n * 512 + k0) = pack_bf16(a0 - bf2f(h0), a1 - bf2f(h1));
}

// ---------------- MFMA GEMM (verified R10; swizzle exact: 1568 = 8*196) ----------------
template <int TR>
__launch_bounds__(256, 2)
__global__ void k_mfma(const ushort* __restrict__ Ahi, const ushort* __restrict__ Alo,
                       const ushort* __restrict__ BhT, const ushort* __restrict__ BlT,
                       ushort* __restrict__ C) {
  __shared__ __align__(16) char lds[65536];
  char* sA0 = lds;
  char* sA1 = lds + 16384;
  char* sB0 = lds + 32768;
  char* sB1 = lds + 49152;
  const int tid = threadIdx.x;
  const int lane = tid & 63, w = tid >> 6;
  const int lid = blockIdx.y * 4 + blockIdx.x;
  const int xcd = lid & 7, pos = lid >> 3;
  const int orig = xcd * 196 + pos;
  const int m0 = (orig >> 2) * 128, n0 = (orig & 3) * 128;
  const int aR0 = (w & 1) * 64, bR0 = (w >> 1) * 64;

  f32x4 acc[4][4];
  const f32x4 z4 = {0.f, 0.f, 0.f, 0.f};
#pragma unroll
  for (int i = 0; i < 4; ++i)
#pragma unroll
    for (int j = 0; j < 4; ++j) acc[i][j] = z4;

#define STAGE_ALL(KT)                                                                     \
  {                                                                                       \
    _Pragma("unroll") for (int i = 0; i < 4; ++i) {                                       \
      const int row = i * 32 + (tid >> 3);                                                \
      const int kb = ((tid & 7) << 4) ^ ((row & 7) << 4);                                 \
      const int ldso = i * 4096 + (w << 10);                                              \
      gl_lds16((const char*)(Ahi + ((size_t)(m0 + row) << 9) + (KT)) + kb, sA0 + ldso);   \
      gl_lds16((const char*)(Alo + ((size_t)(m0 + row) << 9) + (KT)) + kb, sA1 + ldso);   \
      gl_lds16((const char*)(BhT + ((size_t)(n0 + row) << 9) + (KT)) + kb, sB0 + ldso);   \
      gl_lds16((const char*)(BlT + ((size_t)(n0 + row) << 9) + (KT)) + kb, sB1 + ldso);   \
    }                                                                                     \
  }

  STAGE_ALL(0)
  __syncthreads();
  for (int c = 0; c < 8; ++c) {
#pragma unroll
    for (int ks = 0; ks < 2; ++ks) {
      short8 ah[4], al[4], bh[4], bl[4];
      const int kbb = ks * 64 + ((lane >> 4) << 4);
#pragma unroll
      for (int f = 0; f < 4; ++f) {
        const int ra = aR0 + f * 16 + (lane & 15);
        const int oa = ra * 128 + (kbb ^ ((ra & 7) << 4));
        ah[f] = *(const short8*)(sA0 + oa);
        al[f] = *(const short8*)(sA1 + oa);
        const int rb = bR0 + f * 16 + (lane & 15);
        const int ob = rb * 128 + (kbb ^ ((rb & 7) << 4));
        bh[f] = *(const short8*)(sB0 + ob);
        bl[f] = *(const short8*)(sB1 + ob);
      }
#pragma unroll
      for (int mf = 0; mf < 4; ++mf)
#pragma unroll
        for (int nf = 0; nf < 4; ++nf) {
          acc[mf][nf] = MFMA(ah[mf], bh[nf], acc[mf][nf]);
          acc[mf][nf] = MFMA(ah[mf], bl[nf], acc[mf][nf]);
          acc[mf][nf] = MFMA(al[mf], bh[nf], acc[mf][nf]);
        }
    }
    if (c < 7) {
      __syncthreads();
      STAGE_ALL((c + 1) * 64)
      __syncthreads();
    }
  }
#undef STAGE_ALL

#pragma unroll
  for (int mf = 0; mf < 4; ++mf)
#pragma unroll
    for (int nf = 0; nf < 4; ++nf) {
      const f32x4 a = acc[mf][nf];
      const int n = n0 + bR0 + nf * 16 + (lane & 15);
      const int mb = m0 + aR0 + mf * 16 + ((lane >> 4) << 2);
      if (TR) {
        ushort* p = C + (size_t)n * NP + mb;
        *(uint2*)p = make_uint2(pack_bf16(a.x, a.y), pack_bf16(a.z, a.w));
      } else {
        C[(size_t)(mb + 0) * 512 + n] = rne1(a.x);
        C[(size_t)(mb + 1) * 512 + n] = rne1(a.y);
        C[(size_t)(mb + 2) * 512 + n] = rne1(a.z);
        C[(size_t)(mb + 3) * 512 + n] = rne1(a.w);
      }
    }
}

// ---------------- zero sel + counters/flags ----------------
// cnts[0..7]=counters ; cnts[16+t]=flagA ; cnts[32+t]=flagB2
__global__ void k_zero(int* __restrict__ sel, unsigned* __restrict__ cnts) {
  int i = blockIdx.x * 256 + threadIdx.x;
  if (i < NROWS) sel[i] = 0;
  if (blockIdx.x == 0 && threadIdx.x < 80) cnts[threadIdx.x] = 0;
}

// ================= A: LSTM gates + h,c; last-16 blocks: b1 slices =================
__launch_bounds__(256)
__global__ void k_A(const float* __restrict__ attn_mem, const float* __restrict__ stoprow,
                    const float* __restrict__ init_i, const float* __restrict__ init_h,
                    const float* __restrict__ init_c,
                    const float* __restrict__ w_ih, const float* __restrict__ w_hh,
                    const float* __restrict__ b_ih, const float* __restrict__ b_hh,
                    const float* __restrict__ hop_wq,
                    float* __restrict__ hv0, float* __restrict__ hv1,
                    float* __restrict__ cv0, float* __restrict__ cv1,
                    float* __restrict__ b1, const int* __restrict__ xrow_buf,
                    unsigned* __restrict__ cntA, unsigned* __restrict__ flagA, int t) {
  __shared__ float g4[4];
  __shared__ float hs[512];
  __shared__ float red2[256];
  __shared__ int sOld;
  const int b = blockIdx.x, tid = threadIdx.x, w = tid >> 6, lane = tid & 63;
  const int xrow = (t == 0) ? -1 : *xrow_buf;
  const float* xp = (xrow < 0) ? init_i
                               : ((xrow == NITEMS) ? stoprow : attn_mem + (size_t)xrow * DD);
  const float* hsrc = (t == 0) ? init_h : ((t & 1) ? hv0 : hv1);
  float* hdst = (t & 1) ? hv1 : hv0;
  const float* csrc = (t == 0) ? init_c : ((t & 1) ? cv0 : cv1);
  float* cdst = (t & 1) ? cv1 : cv0;

  const int r = w * 512 + b;  // gate section w, unit b
  const float4* x4 = (const float4*)xp;
  const float4* h4 = (const float4*)hsrc;
  const float4* wi = (const float4*)(w_ih + (size_t)r * DD);
  const float4* wh = (const float4*)(w_hh + (size_t)r * DD);
  float s = 0.f;
  float4 a, ww;
  a = x4[lane * 2];     ww = wi[lane * 2];     s += a.x * ww.x + a.y * ww.y + a.z * ww.z + a.w * ww.w;
  a = x4[lane * 2 + 1]; ww = wi[lane * 2 + 1]; s += a.x * ww.x + a.y * ww.y + a.z * ww.z + a.w * ww.w;
  a = h4[lane * 2];     ww = wh[lane * 2];     s += a.x * ww.x + a.y * ww.y + a.z * ww.z + a.w * ww.w;
  a = h4[lane * 2 + 1]; ww = wh[lane * 2 + 1]; s += a.x * ww.x + a.y * ww.y + a.z * ww.z + a.w * ww.w;
#pragma unroll
  for (int off = 32; off > 0; off >>= 1) s += __shfl_xor(s, off);
  if (lane == 0) g4[w] = s + b_ih[r] + b_hh[r];
  __syncthreads();
  if (tid == 0) {
    const float si = 1.f / (1.f + expf(-g4[0]));
    const float sf = 1.f / (1.f + expf(-g4[1]));
    const float so = 1.f / (1.f + expf(-g4[3]));
    const float cn = sf * csrc[b] + si * tanhf(g4[2]);
    cdst[b] = cn;
    hdst[b] = so * tanhf(cn);
  }
  __syncthreads();
  if (tid == 0) {
    __threadfence();
    unsigned old = atomicAdd(cntA, 1u);
    if (old == 511u) { atomicExch(flagA, 1u); *cntA = 0u; }
    sOld = (int)old;
  }
  __syncthreads();
  const int old = sOld;
  if (old >= 496) {
    if (tid == 0 && old != 511) {
      while (atomicAdd(flagA, 0u) == 0u) {}
    }
    __syncthreads();
    __threadfence();
    const int c0 = (old - 496) * 32;
    hs[tid] = hdst[tid];
    hs[tid + 256] = hdst[tid + 256];
    __syncthreads();
    const int col = c0 + (tid & 31), seg = tid >> 5;  // 8 segs x 64
    float acc = 0.f;
#pragma unroll 8
    for (int i = seg * 64; i < seg * 64 + 64; ++i)
      acc = fmaf(hs[i], hop_wq[(size_t)i * 512 + col], acc);
    red2[tid] = acc;
    __syncthreads();
    if (tid < 32) {
      float sm = 0.f;
#pragma unroll
      for (int g2 = 0; g2 < 8; ++g2) sm += red2[tid + 32 * g2];
      b1[c0 + tid] = sm;
    }
  }
}

// ================= B1: hop scores (transposed sweep) -> e[m], Zt =================
__launch_bounds__(512)
__global__ void k_B1(const ushort* __restrict__ featT, const float* __restrict__ b1v,
                     const float* __restrict__ hv, float* __restrict__ e,
                     float* __restrict__ bZ1, float* __restrict__ Zt,
                     unsigned* __restrict__ cntB1) {
  __shared__ float spart[8][256];
  __shared__ float rz[512];
  __shared__ int isLast;
  const int tid = threadIdx.x, g = blockIdx.x;
  const int w = tid >> 6, lane = tid & 63;
  const int mb = g * 256 + lane * 4;
  const int h0 = w * 64;
  const ushort* fp = featT + (size_t)h0 * NP + mb;
  float a0 = 0.f, a1 = 0.f, a2 = 0.f, a3 = 0.f;
#pragma unroll 8
  for (int hh = 0; hh < 64; ++hh) {
    const uint2 u = *(const uint2*)fp;
    fp += NP;
    const float bb = b1v[h0 + hh], vv = hv[h0 + hh];
    a0 += ftanh(bflo(u.x) + bb) * vv;
    a1 += ftanh(bfhi(u.x) + bb) * vv;
    a2 += ftanh(bflo(u.y) + bb) * vv;
    a3 += ftanh(bfhi(u.y) + bb) * vv;
  }
  spart[w][lane * 4 + 0] = a0;
  spart[w][lane * 4 + 1] = a1;
  spart[w][lane * 4 + 2] = a2;
  spart[w][lane * 4 + 3] = a3;
  __syncthreads();
  if (w < 4) {
    const int idx = w * 64 + lane;  // 0..255
    const int m = g * 256 + idx;
    float s = 0.f;
#pragma unroll
    for (int w2 = 0; w2 < 8; ++w2) s += spart[w2][idx];
    float ev = (m < NROWS) ? fexp(s) : 0.f;
    e[m] = ev;
    float Z = ev;
#pragma unroll
    for (int off = 32; off > 0; off >>= 1) Z += __shfl_xor(Z, off);
    if (lane == 0) bZ1[g * 4 + w] = Z;
  }
  __syncthreads();
  if (tid == 0) {
    __threadfence();
    unsigned old = atomicAdd(cntB1, 1u);
    isLast = (old == gridDim.x - 1);
    if (isLast) *cntB1 = 0u;
  }
  __syncthreads();
  if (isLast) {
    __threadfence();
    float Zl = 0.f;
    for (int i = tid; i < NGRP; i += 512) Zl += bZ1[i];
    rz[tid] = Zl;
    __syncthreads();
    for (int s2 = 256; s2 > 0; s2 >>= 1) {
      if (tid < s2) rz[tid] += rz[tid + s2];
      __syncthreads();
    }
    if (tid == 0) *Zt = rz[0];
  }
}

// ================= B2: qn[h] = (e . featT[h]) / Zt ; last-8 blocks: b2 slices =================
__launch_bounds__(256)
__global__ void k_B2(const ushort* __restrict__ featT, const float* __restrict__ e,
                     const float* __restrict__ Zt, const float* __restrict__ attn_wq,
                     float* __restrict__ qn, float* __restrict__ b2,
                     unsigned* __restrict__ cntB2, unsigned* __restrict__ flagB2) {
  __shared__ float red[256];
  __shared__ int sOld;
  const int tid = threadIdx.x, h = blockIdx.x;
  const ushort* fr = featT + (size_t)h * NP;
  float acc = 0.f;
  for (int m0 = tid * 8; m0 < NP; m0 += 2048) {
    const uint4 F = *(const uint4*)(fr + m0);
    const float4 e0 = *(const float4*)(e + m0);
    const float4 e1 = *(const float4*)(e + m0 + 4);
    acc += bflo(F.x) * e0.x + bfhi(F.x) * e0.y + bflo(F.y) * e0.z + bfhi(F.y) * e0.w +
           bflo(F.z) * e1.x + bfhi(F.z) * e1.y + bflo(F.w) * e1.z + bfhi(F.w) * e1.w;
  }
  red[tid] = acc;
  __syncthreads();
  for (int s2 = 128; s2 > 0; s2 >>= 1) {
    if (tid < s2) red[tid] += red[tid + s2];
    __syncthreads();
  }
  if (tid == 0) qn[h] = red[0] / (*Zt);
  __syncthreads();
  if (tid == 0) {
    __threadfence();
    unsigned old = atomicAdd(cntB2, 1u);
    if (old == 511u) { atomicExch(flagB2, 1u); *cntB2 = 0u; }
    sOld = (int)old;
  }
  __syncthreads();
  const int old = sOld;
  if (old >= 504) {
    const int li = old - 504;
    if (tid == 0 && old != 511) {
      while (atomicAdd(flagB2, 0u) == 0u) {}
    }
    __syncthreads();
    __threadfence();
    // b2 slice [li*64, +64): 4 segs x 128 i
    const int j = li * 64 + (tid & 63), is = tid >> 6;
    float a = 0.f;
#pragma unroll 8
    for (int i2 = is * 128; i2 < is * 128 + 128; ++i2)
      a = fmaf(qn[i2], attn_wq[(size_t)i2 * 512 + j], a);
    red[tid] = a;
    __syncthreads();
    if (tid < 64) b2[li * 64 + tid] = red[tid] + red[tid + 64] + red[tid + 128] + red[tid + 192];
  }
}

// ================= C: attn transposed sweep; last block: sample + outputs =================
__launch_bounds__(512)
__global__ void k_C(const ushort* __restrict__ featT, const float* __restrict__ b2,
                    const float* __restrict__ av, int* __restrict__ sel,
                    const float* __restrict__ gum, float* __restrict__ sc,
                    float* __restrict__ bZa, ull* __restrict__ bkey,
                    int* __restrict__ done_buf, int* __restrict__ xrow_buf,
                    float* __restrict__ outf, unsigned* __restrict__ cntC, int t) {
  __shared__ float spart[8][256];
  __shared__ float rz[512];
  __shared__ ull rk[512];
  __shared__ int isLast;
  const int tid = threadIdx.x, g = blockIdx.x;
  const int w = tid >> 6, lane = tid & 63;
  const int mb = g * 256 + lane * 4;
  const int h0 = w * 64;
  const ushort* fp = featT + (size_t)h0 * NP + mb;
  float a0 = 0.f, a1 = 0.f, a2 = 0.f, a3 = 0.f;
#pragma unroll 8
  for (int hh = 0; hh < 64; ++hh) {
    const uint2 u = *(const uint2*)fp;
    fp += NP;
    const float bb = b2[h0 + hh], vv = av[h0 + hh];
    a0 += ftanh(bflo(u.x) + bb) * vv;
    a1 += ftanh(bfhi(u.x) + bb) * vv;
    a2 += ftanh(bflo(u.y) + bb) * vv;
    a3 += ftanh(bfhi(u.y) + bb) * vv;
  }
  spart[w][lane * 4 + 0] = a0;
  spart[w][lane * 4 + 1] = a1;
  spart[w][lane * 4 + 2] = a2;
  spart[w][lane * 4 + 3] = a3;
  __syncthreads();
  if (w < 4) {
    const int idx = w * 64 + lane;  // 0..255
    const int m = g * 256 + idx;
    float s = 0.f;
#pragma unroll
    for (int w2 = 0; w2 < 8; ++w2) s += spart[w2][idx];
    const bool valid = (m < NROWS);
    float Z;
    ull key;
    if (valid) {
      float se = sel[m] ? NEGV : s;
      sc[m] = se;
      key = ((ull)fkey(se + gum[m]) << 32) | (unsigned)(NITEMS - m);
      Z = fexp(se);
    } else {
      key = 0;
      Z = 0.f;
    }
#pragma unroll
    for (int off = 32; off > 0; off >>= 1) {
      Z += __shfl_xor(Z, off);
      ull Ko = __shfl_xor(key, off);
      if (Ko > key) key = Ko;
    }
    if (lane == 0) { bZa[g * 4 + w] = Z; bkey[g * 4 + w] = key; }
  }
  __syncthreads();
  if (tid == 0) {
    __threadfence();
    unsigned old = atomicAdd(cntC, 1u);
    isLast = (old == gridDim.x - 1);
    if (isLast) *cntC = 0u;
  }
  __syncthreads();
  if (isLast) {
    __threadfence();
    float Zl = 0.f;
    ull Kl = 0;
    for (int i = tid; i < NGRP; i += 512) {
      Zl += bZa[i];
      ull k = bkey[i];
      if (k > Kl) Kl = k;
    }
    rz[tid] = Zl;
    rk[tid] = Kl;
    __syncthreads();
    for (int s2 = 256; s2 > 0; s2 >>= 1) {
      if (tid < s2) {
        rz[tid] += rz[tid + s2];
        if (rk[tid + s2] > rk[tid]) rk[tid] = rk[tid + s2];
      }
      __syncthreads();
    }
    if (tid == 0) {
      const float Z = rz[0];
      const ull K = rk[0];
      const int out = NITEMS - (int)(unsigned)(K & 0xffffffffull);
      const int d_in = (t == 0) ? 0 : *done_buf;
      const int xprev = (t == 0) ? -1 : *xrow_buf;
      const int nd = d_in | (out == NITEMS);
      outf[t] = (float)(d_in ? NITEMS : out);
      outf[TT + t] = d_in ? 0.f : (sc[out] - logf(Z));
      if (!d_in) sel[out] = 1;
      *done_buf = nd;
      *xrow_buf = nd ? xprev : out;
    }
  }
}

// ======================================================================
extern "C" void kernel_launch(void* const* d_in, const int* in_sizes, int n_in,
                              void* d_out, int out_size, void* d_ws, size_t ws_size,
                              hipStream_t stream) {
  const float* attn_mem = (const float*)d_in[0];
  const float* stoprow  = (const float*)d_in[1];
  const float* init_h   = (const float*)d_in[2];
  const float* init_c   = (const float*)d_in[3];
  const float* init_i   = (const float*)d_in[4];
  const float* attn_wm  = (const float*)d_in[5];
  const float* attn_wq  = (const float*)d_in[6];
  const float* attn_v   = (const float*)d_in[7];
  const float* hop_wm   = (const float*)d_in[8];
  const float* hop_wq   = (const float*)d_in[9];
  const float* hop_v    = (const float*)d_in[10];
  const float* w_ih     = (const float*)d_in[11];
  const float* w_hh     = (const float*)d_in[12];
  const float* b_ih     = (const float*)d_in[13];
  const float* b_hh     = (const float*)d_in[14];
  const float* gumbel   = (const float*)d_in[15];

  float* ws = (float*)d_ws;
  size_t fo = 0;
  const size_t FB = (size_t)NP * 512 / 2;
  ushort* hop_featT  = (ushort*)(ws + fo); fo += FB;
  ushort* attn_featT = (ushort*)(ws + fo); fo += FB;
  ushort* Ahi = (ushort*)(ws + fo); fo += FB;
  ushort* Alo = (ushort*)(ws + fo); fo += FB;
  ushort* WhiT_a = (ushort*)(ws + fo); fo += 131072;
  ushort* WloT_a = (ushort*)(ws + fo); fo += 131072;
  ushort* WhiT_h = (ushort*)(ws + fo); fo += 131072;
  ushort* WloT_h = (ushort*)(ws + fo); fo += 131072;
  float* sc  = ws + fo; fo += NP;
  int* sel   = (int*)(ws + fo); fo += NP;
  float* e   = ws + fo; fo += NP;
  float* bZ1 = ws + fo; fo += 1024;
  float* bZa = ws + fo; fo += 1024;
  ull* bkey  = (ull*)(ws + fo); fo += 2048;
  float* hv0 = ws + fo; fo += HH;
  float* hv1 = ws + fo; fo += HH;
  float* cv0 = ws + fo; fo += HH;
  float* cv1 = ws + fo; fo += HH;
  float* b1  = ws + fo; fo += HH;
  float* b2  = ws + fo; fo += HH;
  float* qn  = ws + fo; fo += HH;
  float* Ztp = ws + fo; fo += 2;
  unsigned* cnts = (unsigned*)(ws + fo); fo += 80;
  int* done_buf = (int*)(ws + fo); fo += 2;
  int* xrow_buf = (int*)(ws + fo); fo += 2;
  if (fo * sizeof(float) > ws_size) return;

  float* outf = (float*)d_out;

  k_zero<<<NP / 256, 256, 0, stream>>>(sel, cnts);
  k_convA<<<(NP * 512 / 8) / 256, 256, 0, stream>>>(attn_mem, stoprow, Ahi, Alo);
  k_convBT<<<512, 256, 0, stream>>>(attn_wm, WhiT_a, WloT_a);
  k_convBT<<<512, 256, 0, stream>>>(hop_wm, WhiT_h, WloT_h);

  dim3 ggrid(4, NP / 128);  // 1568 blocks = 8*196
  k_mfma<1><<<ggrid, 256, 0, stream>>>(Ahi, Alo, WhiT_a, WloT_a, attn_featT);
  k_mfma<1><<<ggrid, 256, 0, stream>>>(Ahi, Alo, WhiT_h, WloT_h, hop_featT);

  for (int t = 0; t < TT; ++t) {
    k_A<<<512, 256, 0, stream>>>(attn_mem, stoprow, init_i, init_h, init_c,
                                 w_ih, w_hh, b_ih, b_hh, hop_wq,
                                 hv0, hv1, cv0, cv1, b1, xrow_buf,
                                 cnts + 0, cnts + 16 + t, t);
    k_B1<<<NGC, 512, 0, stream>>>(hop_featT, b1, hop_v, e, bZ1, Ztp, cnts + 1);
    k_B2<<<512, 256, 0, stream>>>(hop_featT, e, Ztp, attn_wq, qn, b2,
                                  cnts + 3, cnts + 32 + t);
    k_C<<<NGC, 512, 0, stream>>>(attn_featT, b2, attn_v, sel,
                                 gumbel + (size_t)t * NROWS, sc, bZa, bkey,
                                 done_buf, xrow_buf, outf, cnts + 2, t);
  }
}

// Round 16
// 1623.693 us; speedup vs baseline: 3.1111x; 1.0076x over previous
//
#include <hip/hip_runtime.h>
#include <math.h>

#define NITEMS 50000
#define NROWS 50001
#define NP 50176          // padded row count (392*128 = 196*256)
#define DD 512
#define HH 512
#define TT 16
#define NEGV (-1e18f)
#define NGRP 784          // 196 blocks x 4 partials
#define NGC 196           // transposed-sweep blocks (256 rows each)

typedef unsigned long long ull;
typedef unsigned short ushort;
typedef short short8 __attribute__((ext_vector_type(8)));
typedef float f32x4 __attribute__((ext_vector_type(4)));

// ---- scoped-atomic helpers (agent scope, no cache-nuking threadfence) ----
#define AST(p, v) __hip_atomic_store((p), (v), __ATOMIC_RELAXED, __HIP_MEMORY_SCOPE_AGENT)
#define ALD(p) __hip_atomic_load((p), __ATOMIC_RELAXED, __HIP_MEMORY_SCOPE_AGENT)
#define AADD_REL(p) __hip_atomic_fetch_add((p), 1u, __ATOMIC_ACQ_REL, __HIP_MEMORY_SCOPE_AGENT)
#define FLAG_SET(p) __hip_atomic_store((p), 1u, __ATOMIC_RELEASE, __HIP_MEMORY_SCOPE_AGENT)
#define FLAG_GET(p) __hip_atomic_load((p), __ATOMIC_ACQUIRE, __HIP_MEMORY_SCOPE_AGENT)

__device__ __forceinline__ unsigned fkey(float f) {
  unsigned u = __float_as_uint(f);
  return (u & 0x80000000u) ? ~u : (u | 0x80000000u);
}
__device__ __forceinline__ float ftanh(float x) {
  float e = __builtin_amdgcn_exp2f(x * 2.885390081777927f);
  return 1.f - 2.f * __builtin_amdgcn_rcpf(e + 1.f);
}
__device__ __forceinline__ float fexp(float x) {
  return __builtin_amdgcn_exp2f(x * 1.4426950408889634f);
}
__device__ __forceinline__ ushort rne1(float a) {
  unsigned u = __float_as_uint(a);
  return (ushort)((u + 0x7fffu + ((u >> 16) & 1u)) >> 16);
}
__device__ __forceinline__ float bf2f(ushort h) { return __uint_as_float((unsigned)h << 16); }
__device__ __forceinline__ unsigned pack_bf16(float a, float b) {
  return (unsigned)rne1(a) | ((unsigned)rne1(b) << 16);
}
__device__ __forceinline__ float bflo(unsigned u) { return __uint_as_float(u << 16); }
__device__ __forceinline__ float bfhi(unsigned u) { return __uint_as_float(u & 0xffff0000u); }

__device__ __forceinline__ void gl_lds16(const void* g, void* l) {
#if __has_builtin(__builtin_amdgcn_global_load_lds)
  __builtin_amdgcn_global_load_lds((const __attribute__((address_space(1))) unsigned*)g,
                                   (__attribute__((address_space(3))) unsigned*)l, 16, 0, 0);
#else
  const int lane = threadIdx.x & 63;
  *(uint4*)((char*)l + lane * 16) = *(const uint4*)g;
#endif
}

#define MFMA(a, b, c) __builtin_amdgcn_mfma_f32_16x16x32_bf16(a, b, c, 0, 0, 0)

// ---------------- A -> (Ahi, Alo) bf16 [NP][512] ----------------
__global__ void k_convA(const float* __restrict__ A0, const float* __restrict__ stoprow,
                        ushort* __restrict__ Ahi, ushort* __restrict__ Alo) {
  const size_t t = (size_t)blockIdx.x * 256 + threadIdx.x;
  const size_t base = t * 8;
  const int row = (int)(base >> 9);
  float v[8];
  if (row < NITEMS) {
    const float4* p = (const float4*)(A0 + base);
    float4 x = p[0], y = p[1];
    v[0] = x.x; v[1] = x.y; v[2] = x.z; v[3] = x.w;
    v[4] = y.x; v[5] = y.y; v[6] = y.z; v[7] = y.w;
  } else if (row == NITEMS) {
    const float4* p = (const float4*)(stoprow + (base & 511));
    float4 x = p[0], y = p[1];
    v[0] = x.x; v[1] = x.y; v[2] = x.z; v[3] = x.w;
    v[4] = y.x; v[5] = y.y; v[6] = y.z; v[7] = y.w;
  } else {
#pragma unroll
    for (int j = 0; j < 8; ++j) v[j] = 0.f;
  }
  unsigned hw[4], lw[4];
#pragma unroll
  for (int j = 0; j < 4; ++j) {
    float a0 = v[2 * j], a1 = v[2 * j + 1];
    ushort h0 = rne1(a0), h1 = rne1(a1);
    hw[j] = (unsigned)h0 | ((unsigned)h1 << 16);
    lw[j] = pack_bf16(a0 - bf2f(h0), a1 - bf2f(h1));
  }
  *(uint4*)(Ahi + base) = make_uint4(hw[0], hw[1], hw[2], hw[3]);
  *(uint4*)(Alo + base) = make_uint4(lw[0], lw[1], lw[2], lw[3]);
}

// ---------------- W [k][n] -> transposed bf16 ----------------
__global__ void k_convBT(const float* __restrict__ W, ushort* __restrict__ WhiT,
                         ushort* __restrict__ WloT) {
  const int n = blockIdx.x;
  const int k0 = threadIdx.x * 2;
  float a0 = W[(size_t)k0 * 512 + n];
  float a1 = W[(size_t)(k0 + 1) * 512 + n];
  ushort h0 = rne1(a0), h1 = rne1(a1);
  *(unsigned*)(WhiT + (size_t)n * 512 + k0) = (unsigned)h0 | ((unsigned)h1 << 16);
  *(unsigned*)(WloT + (size_t)n * 512 + k0) = pack_bf16(a0 - bf2f(h0), a1 - bf2f(h1));
}

// ---------------- MFMA GEMM (verified R10; swizzle exact: 1568 = 8*196) ----------------
template <int TR>
__launch_bounds__(256, 2)
__global__ void k_mfma(const ushort* __restrict__ Ahi, const ushort* __restrict__ Alo,
                       const ushort* __restrict__ BhT, const ushort* __restrict__ BlT,
                       ushort* __restrict__ C) {
  __shared__ __align__(16) char lds[65536];
  char* sA0 = lds;
  char* sA1 = lds + 16384;
  char* sB0 = lds + 32768;
  char* sB1 = lds + 49152;
  const int tid = threadIdx.x;
  const int lane = tid & 63, w = tid >> 6;
  const int lid = blockIdx.y * 4 + blockIdx.x;
  const int xcd = lid & 7, pos = lid >> 3;
  const int orig = xcd * 196 + pos;
  const int m0 = (orig >> 2) * 128, n0 = (orig & 3) * 128;
  const int aR0 = (w & 1) * 64, bR0 = (w >> 1) * 64;

  f32x4 acc[4][4];
  const f32x4 z4 = {0.f, 0.f, 0.f, 0.f};
#pragma unroll
  for (int i = 0; i < 4; ++i)
#pragma unroll
    for (int j = 0; j < 4; ++j) acc[i][j] = z4;

#define STAGE_ALL(KT)                                                                     \
  {                                                                                       \
    _Pragma("unroll") for (int i = 0; i < 4; ++i) {                                       \
      const int row = i * 32 + (tid >> 3);                                                \
      const int kb = ((tid & 7) << 4) ^ ((row & 7) << 4);                                 \
      const int ldso = i * 4096 + (w << 10);                                              \
      gl_lds16((const char*)(Ahi + ((size_t)(m0 + row) << 9) + (KT)) + kb, sA0 + ldso);   \
      gl_lds16((const char*)(Alo + ((size_t)(m0 + row) << 9) + (KT)) + kb, sA1 + ldso);   \
      gl_lds16((const char*)(BhT + ((size_t)(n0 + row) << 9) + (KT)) + kb, sB0 + ldso);   \
      gl_lds16((const char*)(BlT + ((size_t)(n0 + row) << 9) + (KT)) + kb, sB1 + ldso);   \
    }                                                                                     \
  }

  STAGE_ALL(0)
  __syncthreads();
  for (int c = 0; c < 8; ++c) {
#pragma unroll
    for (int ks = 0; ks < 2; ++ks) {
      short8 ah[4], al[4], bh[4], bl[4];
      const int kbb = ks * 64 + ((lane >> 4) << 4);
#pragma unroll
      for (int f = 0; f < 4; ++f) {
        const int ra = aR0 + f * 16 + (lane & 15);
        const int oa = ra * 128 + (kbb ^ ((ra & 7) << 4));
        ah[f] = *(const short8*)(sA0 + oa);
        al[f] = *(const short8*)(sA1 + oa);
        const int rb = bR0 + f * 16 + (lane & 15);
        const int ob = rb * 128 + (kbb ^ ((rb & 7) << 4));
        bh[f] = *(const short8*)(sB0 + ob);
        bl[f] = *(const short8*)(sB1 + ob);
      }
#pragma unroll
      for (int mf = 0; mf < 4; ++mf)
#pragma unroll
        for (int nf = 0; nf < 4; ++nf) {
          acc[mf][nf] = MFMA(ah[mf], bh[nf], acc[mf][nf]);
          acc[mf][nf] = MFMA(ah[mf], bl[nf], acc[mf][nf]);
          acc[mf][nf] = MFMA(al[mf], bh[nf], acc[mf][nf]);
        }
    }
    if (c < 7) {
      __syncthreads();
      STAGE_ALL((c + 1) * 64)
      __syncthreads();
    }
  }
#undef STAGE_ALL

#pragma unroll
  for (int mf = 0; mf < 4; ++mf)
#pragma unroll
    for (int nf = 0; nf < 4; ++nf) {
      const f32x4 a = acc[mf][nf];
      const int n = n0 + bR0 + nf * 16 + (lane & 15);
      const int mb = m0 + aR0 + mf * 16 + ((lane >> 4) << 2);
      if (TR) {
        ushort* p = C + (size_t)n * NP + mb;
        *(uint2*)p = make_uint2(pack_bf16(a.x, a.y), pack_bf16(a.z, a.w));
      } else {
        C[(size_t)(mb + 0) * 512 + n] = rne1(a.x);
        C[(size_t)(mb + 1) * 512 + n] = rne1(a.y);
        C[(size_t)(mb + 2) * 512 + n] = rne1(a.z);
        C[(size_t)(mb + 3) * 512 + n] = rne1(a.w);
      }
    }
}

// ---------------- zero sel + counters/flags ----------------
__global__ void k_zero(int* __restrict__ sel, unsigned* __restrict__ cnts) {
  int i = blockIdx.x * 256 + threadIdx.x;
  if (i < NROWS) sel[i] = 0;
  if (blockIdx.x == 0 && threadIdx.x < 80) cnts[threadIdx.x] = 0;
}

// ================= A: LSTM gates + h,c; last-16 blocks: b1 slices =================
__launch_bounds__(256)
__global__ void k_A(const float* __restrict__ attn_mem, const float* __restrict__ stoprow,
                    const float* __restrict__ init_i, const float* __restrict__ init_h,
                    const float* __restrict__ init_c,
                    const float* __restrict__ w_ih, const float* __restrict__ w_hh,
                    const float* __restrict__ b_ih, const float* __restrict__ b_hh,
                    const float* __restrict__ hop_wq,
                    float* __restrict__ hv0, float* __restrict__ hv1,
                    float* __restrict__ cv0, float* __restrict__ cv1,
                    float* __restrict__ b1, const int* __restrict__ xrow_buf,
                    unsigned* __restrict__ cntA, unsigned* __restrict__ flagA, int t) {
  __shared__ float g4[4];
  __shared__ float hs[512];
  __shared__ float red2[256];
  __shared__ int sOld;
  const int b = blockIdx.x, tid = threadIdx.x, w = tid >> 6, lane = tid & 63;
  const int xrow = (t == 0) ? -1 : *xrow_buf;
  const float* xp = (xrow < 0) ? init_i
                               : ((xrow == NITEMS) ? stoprow : attn_mem + (size_t)xrow * DD);
  const float* hsrc = (t == 0) ? init_h : ((t & 1) ? hv0 : hv1);
  float* hdst = (t & 1) ? hv1 : hv0;
  const float* csrc = (t == 0) ? init_c : ((t & 1) ? cv0 : cv1);
  float* cdst = (t & 1) ? cv1 : cv0;

  const int r = w * 512 + b;  // gate section w, unit b
  const float4* x4 = (const float4*)xp;
  const float4* h4 = (const float4*)hsrc;
  const float4* wi = (const float4*)(w_ih + (size_t)r * DD);
  const float4* wh = (const float4*)(w_hh + (size_t)r * DD);
  float s = 0.f;
  float4 a, ww;
  a = x4[lane * 2];     ww = wi[lane * 2];     s += a.x * ww.x + a.y * ww.y + a.z * ww.z + a.w * ww.w;
  a = x4[lane * 2 + 1]; ww = wi[lane * 2 + 1]; s += a.x * ww.x + a.y * ww.y + a.z * ww.z + a.w * ww.w;
  a = h4[lane * 2];     ww = wh[lane * 2];     s += a.x * ww.x + a.y * ww.y + a.z * ww.z + a.w * ww.w;
  a = h4[lane * 2 + 1]; ww = wh[lane * 2 + 1]; s += a.x * ww.x + a.y * ww.y + a.z * ww.z + a.w * ww.w;
#pragma unroll
  for (int off = 32; off > 0; off >>= 1) s += __shfl_xor(s, off);
  if (lane == 0) g4[w] = s + b_ih[r] + b_hh[r];
  __syncthreads();
  if (tid == 0) {
    const float si = 1.f / (1.f + expf(-g4[0]));
    const float sf = 1.f / (1.f + expf(-g4[1]));
    const float so = 1.f / (1.f + expf(-g4[3]));
    const float cn = sf * csrc[b] + si * tanhf(g4[2]);
    cdst[b] = cn;                       // cross-launch consumer only
    AST(&hdst[b], so * tanhf(cn));      // intra-kernel consumer (tails)
  }
  __syncthreads();
  if (tid == 0) {
    unsigned old = AADD_REL(cntA);
    if (old == 511u) { FLAG_SET(flagA); AST(cntA, 0u); }
    sOld = (int)old;
  }
  __syncthreads();
  const int old = sOld;
  if (old >= 496) {
    if (tid == 0 && old != 511) {
      while (FLAG_GET(flagA) == 0u) {}
    }
    __syncthreads();
    const int c0 = (old - 496) * 32;
    hs[tid] = ALD(&hdst[tid]);
    hs[tid + 256] = ALD(&hdst[tid + 256]);
    __syncthreads();
    const int col = c0 + (tid & 31), seg = tid >> 5;  // 8 segs x 64
    float acc = 0.f;
#pragma unroll 8
    for (int i = seg * 64; i < seg * 64 + 64; ++i)
      acc = fmaf(hs[i], hop_wq[(size_t)i * 512 + col], acc);
    red2[tid] = acc;
    __syncthreads();
    if (tid < 32) {
      float sm = 0.f;
#pragma unroll
      for (int g2 = 0; g2 < 8; ++g2) sm += red2[tid + 32 * g2];
      b1[c0 + tid] = sm;  // cross-launch consumer
    }
  }
}

// ================= B1: hop scores (transposed sweep) -> e[m], Zt =================
__launch_bounds__(512)
__global__ void k_B1(const ushort* __restrict__ featT, const float* __restrict__ b1v,
                     const float* __restrict__ hv, float* __restrict__ e,
                     float* __restrict__ bZ1, float* __restrict__ Zt,
                     unsigned* __restrict__ cntB1) {
  __shared__ float spart[8][256];
  __shared__ float rz[512];
  __shared__ int isLast;
  const int tid = threadIdx.x, g = blockIdx.x;
  const int w = tid >> 6, lane = tid & 63;
  const int mb = g * 256 + lane * 4;
  const int h0 = w * 64;
  const ushort* fp = featT + (size_t)h0 * NP + mb;
  float a0 = 0.f, a1 = 0.f, a2 = 0.f, a3 = 0.f;
#pragma unroll 8
  for (int hh = 0; hh < 64; ++hh) {
    const uint2 u = *(const uint2*)fp;
    fp += NP;
    const float bb = b1v[h0 + hh], vv = hv[h0 + hh];
    a0 += ftanh(bflo(u.x) + bb) * vv;
    a1 += ftanh(bfhi(u.x) + bb) * vv;
    a2 += ftanh(bflo(u.y) + bb) * vv;
    a3 += ftanh(bfhi(u.y) + bb) * vv;
  }
  spart[w][lane * 4 + 0] = a0;
  spart[w][lane * 4 + 1] = a1;
  spart[w][lane * 4 + 2] = a2;
  spart[w][lane * 4 + 3] = a3;
  __syncthreads();
  if (w < 4) {
    const int idx = w * 64 + lane;  // 0..255
    const int m = g * 256 + idx;
    float s = 0.f;
#pragma unroll
    for (int w2 = 0; w2 < 8; ++w2) s += spart[w2][idx];
    float ev = (m < NROWS) ? fexp(s) : 0.f;
    e[m] = ev;  // cross-launch consumer (k_B2)
    float Z = ev;
#pragma unroll
    for (int off = 32; off > 0; off >>= 1) Z += __shfl_xor(Z, off);
    if (lane == 0) AST(&bZ1[g * 4 + w], Z);
  }
  __syncthreads();
  if (tid == 0) {
    unsigned old = AADD_REL(cntB1);
    isLast = (old == gridDim.x - 1);
    if (isLast) AST(cntB1, 0u);
  }
  __syncthreads();
  if (isLast) {
    float Zl = 0.f;
    for (int i = tid; i < NGRP; i += 512) Zl += ALD(&bZ1[i]);
    rz[tid] = Zl;
    __syncthreads();
    for (int s2 = 256; s2 > 0; s2 >>= 1) {
      if (tid < s2) rz[tid] += rz[tid + s2];
      __syncthreads();
    }
    if (tid == 0) *Zt = rz[0];  // cross-launch consumer
  }
}

// ================= B2: qn[h] = (e . featT[h]) / Zt ; last-8 blocks: b2 slices =================
__launch_bounds__(256)
__global__ void k_B2(const ushort* __restrict__ featT, const float* __restrict__ e,
                     const float* __restrict__ Zt, const float* __restrict__ attn_wq,
                     float* __restrict__ qn, float* __restrict__ b2,
                     unsigned* __restrict__ cntB2, unsigned* __restrict__ flagB2) {
  __shared__ float red[256];
  __shared__ int sOld;
  const int tid = threadIdx.x, h = blockIdx.x;
  const ushort* fr = featT + (size_t)h * NP;
  float acc = 0.f;
#pragma unroll 4
  for (int m0 = tid * 8; m0 < NP; m0 += 2048) {
    const uint4 F = *(const uint4*)(fr + m0);
    const float4 e0 = *(const float4*)(e + m0);
    const float4 e1 = *(const float4*)(e + m0 + 4);
    acc += bflo(F.x) * e0.x + bfhi(F.x) * e0.y + bflo(F.y) * e0.z + bfhi(F.y) * e0.w +
           bflo(F.z) * e1.x + bfhi(F.z) * e1.y + bflo(F.w) * e1.z + bfhi(F.w) * e1.w;
  }
  red[tid] = acc;
  __syncthreads();
  for (int s2 = 128; s2 > 0; s2 >>= 1) {
    if (tid < s2) red[tid] += red[tid + s2];
    __syncthreads();
  }
  if (tid == 0) AST(&qn[h], red[0] / (*Zt));  // intra-kernel consumer (tails)
  __syncthreads();
  if (tid == 0) {
    unsigned old = AADD_REL(cntB2);
    if (old == 511u) { FLAG_SET(flagB2); AST(cntB2, 0u); }
    sOld = (int)old;
  }
  __syncthreads();
  const int old = sOld;
  if (old >= 504) {
    const int li = old - 504;
    if (tid == 0 && old != 511) {
      while (FLAG_GET(flagB2) == 0u) {}
    }
    __syncthreads();
    // b2 slice [li*64, +64): 4 segs x 128 i
    const int j = li * 64 + (tid & 63), is = tid >> 6;
    float a = 0.f;
#pragma unroll 8
    for (int i2 = is * 128; i2 < is * 128 + 128; ++i2)
      a = fmaf(ALD(&qn[i2]), attn_wq[(size_t)i2 * 512 + j], a);
    red[tid] = a;
    __syncthreads();
    if (tid < 64) b2[li * 64 + tid] = red[tid] + red[tid + 64] + red[tid + 128] + red[tid + 192];
  }
}

// ================= C: attn transposed sweep; score carried with key; last block: sample =================
__launch_bounds__(512)
__global__ void k_C(const ushort* __restrict__ featT, const float* __restrict__ b2,
                    const float* __restrict__ av, int* __restrict__ sel,
                    const float* __restrict__ gum,
                    float* __restrict__ bZa, ull* __restrict__ bkey, float* __restrict__ bsc,
                    int* __restrict__ done_buf, int* __restrict__ xrow_buf,
                    float* __restrict__ outf, unsigned* __restrict__ cntC, int t) {
  __shared__ float spart[8][256];
  __shared__ float rz[512];
  __shared__ ull rk[512];
  __shared__ float rs[512];
  __shared__ int isLast;
  const int tid = threadIdx.x, g = blockIdx.x;
  const int w = tid >> 6, lane = tid & 63;
  const int mb = g * 256 + lane * 4;
  const int h0 = w * 64;
  const ushort* fp = featT + (size_t)h0 * NP + mb;
  float a0 = 0.f, a1 = 0.f, a2 = 0.f, a3 = 0.f;
#pragma unroll 8
  for (int hh = 0; hh < 64; ++hh) {
    const uint2 u = *(const uint2*)fp;
    fp += NP;
    const float bb = b2[h0 + hh], vv = av[h0 + hh];
    a0 += ftanh(bflo(u.x) + bb) * vv;
    a1 += ftanh(bfhi(u.x) + bb) * vv;
    a2 += ftanh(bflo(u.y) + bb) * vv;
    a3 += ftanh(bfhi(u.y) + bb) * vv;
  }
  spart[w][lane * 4 + 0] = a0;
  spart[w][lane * 4 + 1] = a1;
  spart[w][lane * 4 + 2] = a2;
  spart[w][lane * 4 + 3] = a3;
  __syncthreads();
  if (w < 4) {
    const int idx = w * 64 + lane;  // 0..255
    const int m = g * 256 + idx;
    float s = 0.f;
#pragma unroll
    for (int w2 = 0; w2 < 8; ++w2) s += spart[w2][idx];
    const bool valid = (m < NROWS);
    float Z, sv;
    ull key;
    if (valid) {
      const float se = sel[m] ? NEGV : s;
      sv = se;
      key = ((ull)fkey(se + gum[m]) << 32) | (unsigned)(NITEMS - m);
      Z = fexp(se);
    } else {
      key = 0;
      Z = 0.f;
      sv = 0.f;
    }
#pragma unroll
    for (int off = 32; off > 0; off >>= 1) {
      Z += __shfl_xor(Z, off);
      ull Ko = __shfl_xor(key, off);
      float so = __shfl_xor(sv, off);
      if (Ko > key) { key = Ko; sv = so; }
    }
    if (lane == 0) {
      AST(&bZa[g * 4 + w], Z);
      AST(&bkey[g * 4 + w], key);
      AST(&bsc[g * 4 + w], sv);
    }
  }
  __syncthreads();
  if (tid == 0) {
    unsigned old = AADD_REL(cntC);
    isLast = (old == gridDim.x - 1);
    if (isLast) AST(cntC, 0u);
  }
  __syncthreads();
  if (isLast) {
    float Zl = 0.f, Sl = 0.f;
    ull Kl = 0;
    for (int i = tid; i < NGRP; i += 512) {
      Zl += ALD(&bZa[i]);
      ull k = ALD(&bkey[i]);
      if (k > Kl) { Kl = k; Sl = ALD(&bsc[i]); }
    }
    rz[tid] = Zl;
    rk[tid] = Kl;
    rs[tid] = Sl;
    __syncthreads();
    for (int s2 = 256; s2 > 0; s2 >>= 1) {
      if (tid < s2) {
        rz[tid] += rz[tid + s2];
        if (rk[tid + s2] > rk[tid]) { rk[tid] = rk[tid + s2]; rs[tid] = rs[tid + s2]; }
      }
      __syncthreads();
    }
    if (tid == 0) {
      const float Z = rz[0];
      const ull K = rk[0];
      const int out = NITEMS - (int)(unsigned)(K & 0xffffffffull);
      const int d_in = (t == 0) ? 0 : *done_buf;
      const int xprev = (t == 0) ? -1 : *xrow_buf;
      const int nd = d_in | (out == NITEMS);
      outf[t] = (float)(d_in ? NITEMS : out);
      outf[TT + t] = d_in ? 0.f : (rs[0] - logf(Z));
      if (!d_in) sel[out] = 1;
      *done_buf = nd;
      *xrow_buf = nd ? xprev : out;
    }
  }
}

// ======================================================================
extern "C" void kernel_launch(void* const* d_in, const int* in_sizes, int n_in,
                              void* d_out, int out_size, void* d_ws, size_t ws_size,
                              hipStream_t stream) {
  const float* attn_mem = (const float*)d_in[0];
  const float* stoprow  = (const float*)d_in[1];
  const float* init_h   = (const float*)d_in[2];
  const float* init_c   = (const float*)d_in[3];
  const float* init_i   = (const float*)d_in[4];
  const float* attn_wm  = (const float*)d_in[5];
  const float* attn_wq  = (const float*)d_in[6];
  const float* attn_v   = (const float*)d_in[7];
  const float* hop_wm   = (const float*)d_in[8];
  const float* hop_wq   = (const float*)d_in[9];
  const float* hop_v    = (const float*)d_in[10];
  const float* w_ih     = (const float*)d_in[11];
  const float* w_hh     = (const float*)d_in[12];
  const float* b_ih     = (const float*)d_in[13];
  const float* b_hh     = (const float*)d_in[14];
  const float* gumbel   = (const float*)d_in[15];

  float* ws = (float*)d_ws;
  size_t fo = 0;
  const size_t FB = (size_t)NP * 512 / 2;
  ushort* hop_featT  = (ushort*)(ws + fo); fo += FB;
  ushort* attn_featT = (ushort*)(ws + fo); fo += FB;
  ushort* Ahi = (ushort*)(ws + fo); fo += FB;
  ushort* Alo = (ushort*)(ws + fo); fo += FB;
  ushort* WhiT_a = (ushort*)(ws + fo); fo += 131072;
  ushort* WloT_a = (ushort*)(ws + fo); fo += 131072;
  ushort* WhiT_h = (ushort*)(ws + fo); fo += 131072;
  ushort* WloT_h = (ushort*)(ws + fo); fo += 131072;
  int* sel   = (int*)(ws + fo); fo += NP;
  float* e   = ws + fo; fo += NP;
  float* bZ1 = ws + fo; fo += 1024;
  float* bZa = ws + fo; fo += 1024;
  float* bsc = ws + fo; fo += 1024;
  ull* bkey  = (ull*)(ws + fo); fo += 2048;
  float* hv0 = ws + fo; fo += HH;
  float* hv1 = ws + fo; fo += HH;
  float* cv0 = ws + fo; fo += HH;
  float* cv1 = ws + fo; fo += HH;
  float* b1  = ws + fo; fo += HH;
  float* b2  = ws + fo; fo += HH;
  float* qn  = ws + fo; fo += HH;
  float* Ztp = ws + fo; fo += 2;
  unsigned* cnts = (unsigned*)(ws + fo); fo += 80;
  int* done_buf = (int*)(ws + fo); fo += 2;
  int* xrow_buf = (int*)(ws + fo); fo += 2;
  if (fo * sizeof(float) > ws_size) return;

  float* outf = (float*)d_out;

  k_zero<<<NP / 256, 256, 0, stream>>>(sel, cnts);
  k_convA<<<(NP * 512 / 8) / 256, 256, 0, stream>>>(attn_mem, stoprow, Ahi, Alo);
  k_convBT<<<512, 256, 0, stream>>>(attn_wm, WhiT_a, WloT_a);
  k_convBT<<<512, 256, 0, stream>>>(hop_wm, WhiT_h, WloT_h);

  dim3 ggrid(4, NP / 128);  // 1568 blocks = 8*196
  k_mfma<1><<<ggrid, 256, 0, stream>>>(Ahi, Alo, WhiT_a, WloT_a, attn_featT);
  k_mfma<1><<<ggrid, 256, 0, stream>>>(Ahi, Alo, WhiT_h, WloT_h, hop_featT);

  for (int t = 0; t < TT; ++t) {
    k_A<<<512, 256, 0, stream>>>(attn_mem, stoprow, init_i, init_h, init_c,
                                 w_ih, w_hh, b_ih, b_hh, hop_wq,
                                 hv0, hv1, cv0, cv1, b1, xrow_buf,
                                 cnts + 0, cnts + 16 + t, t);
    k_B1<<<NGC, 512, 0, stream>>>(hop_featT, b1, hop_v, e, bZ1, Ztp, cnts + 1);
    k_B2<<<512, 256, 0, stream>>>(hop_featT, e, Ztp, attn_wq, qn, b2,
                                  cnts + 3, cnts + 32 + t);
    k_C<<<NGC, 512, 0, stream>>>(attn_featT, b2, attn_v, sel,
                                 gumbel + (size_t)t * NROWS, bZa, bkey, bsc,
                                 done_buf, xrow_buf, outf, cnts + 2, t);
  }
}